// Round 5
// baseline (403.735 us; speedup 1.0000x reference)
//
#include <hip/hip_runtime.h>
#include <hip/hip_bf16.h>

#define LSEQ 4096
#define BSZ 2
#define DMODEL 512
#define DINNER 1024
#define DSTATE 64
#define NHEADS 16
#define CONVDIM 1152
#define DPROJ 2192
#define NPAD 2304
#define NTOK (BSZ*LSEQ)
#define NCH 64   /* 64-token chunks */

typedef __attribute__((ext_vector_type(8))) short short8;
typedef __attribute__((ext_vector_type(4))) float f32x4;

__device__ inline unsigned short f2b(float v){
  unsigned int u = __builtin_bit_cast(unsigned int, v);
  unsigned int r = (u + 0x7FFFu + ((u >> 16) & 1u)) >> 16;
  return (unsigned short)r;
}
__device__ inline float b2f(unsigned short u){
  unsigned int x = ((unsigned int)u) << 16;
  return __builtin_bit_cast(float, x);
}
__device__ inline uint4 pack8(const float* v){
  uint4 pk;
  pk.x = (unsigned)f2b(v[0]) | ((unsigned)f2b(v[1])<<16);
  pk.y = (unsigned)f2b(v[2]) | ((unsigned)f2b(v[3])<<16);
  pk.z = (unsigned)f2b(v[4]) | ((unsigned)f2b(v[5])<<16);
  pk.w = (unsigned)f2b(v[6]) | ((unsigned)f2b(v[7])<<16);
  return pk;
}
// tanh-form gelu (max abs err ~3e-4 vs exact erf form; far below bf16 noise here)
__device__ inline float gelu_f(float x){
  float x2 = x*x;
  float u = x*(0.7978845608f + 0.0356774081f*x2);
  float au = fabsf(u);
  float z = __expf(-2.f*au);
  float t = (1.f - z)/(1.f + z);
  t = (u >= 0.f) ? t : -t;
  return 0.5f*x*(1.f + t);
}

#define GLL16(gp, lp) __builtin_amdgcn_global_load_lds( \
    (const __attribute__((address_space(1))) unsigned int*)(gp), \
    (__attribute__((address_space(3))) unsigned int*)(lp), 16, 0, 0)

// ---------------- weight transpose + f32->bf16 (src [K][Nsrc] -> dst [Npad][K]) ----
__global__ __launch_bounds__(256) void wconv_t(const float* __restrict__ src,
    unsigned short* __restrict__ dst, int K, int Nsrc, int Npad){
  __shared__ float t[32][33];
  int n0 = blockIdx.x*32, k0 = blockIdx.y*32;
  int tx = threadIdx.x & 31, ty = threadIdx.x >> 5;
  for (int i=0;i<4;i++){
    int k = k0 + ty + i*8; int n = n0 + tx;
    t[ty + i*8][tx] = (n < Nsrc) ? src[(size_t)k*Nsrc + n] : 0.f;
  }
  __syncthreads();
  for (int i=0;i<4;i++){
    int n = n0 + ty + i*8; int k = k0 + tx;
    if (n < Npad) dst[(size_t)n*K + k] = f2b(t[tx][ty + i*8]);
  }
}

// ---------------- layernorm over 512 cols (f32 in) -> bf16 ----------------
__global__ __launch_bounds__(256) void layernorm_k(const float* __restrict__ in,
    const float* __restrict__ w, const float* __restrict__ bb, unsigned short* __restrict__ out){
  int row = blockIdx.x; int tid = threadIdx.x;
  const float* r = in + (size_t)row*DMODEL;
  float v0 = r[tid], v1 = r[tid+256];
  float s = v0+v1, sq = v0*v0+v1*v1;
  for (int m=32;m>=1;m>>=1){ s += __shfl_xor(s,m); sq += __shfl_xor(sq,m); }
  __shared__ float ws_[4], wq_[4];
  int wave = tid>>6, lane = tid&63;
  if (lane==0){ ws_[wave]=s; wq_[wave]=sq; }
  __syncthreads();
  s = ws_[0]+ws_[1]+ws_[2]+ws_[3]; sq = wq_[0]+wq_[1]+wq_[2]+wq_[3];
  float mu = s * (1.f/DMODEL);
  float var = sq * (1.f/DMODEL) - mu*mu;
  float rs = rsqrtf(var + 1e-5f);
  out[(size_t)row*DMODEL + tid]     = f2b((v0-mu)*rs*w[tid] + bb[tid]);
  out[(size_t)row*DMODEL + tid+256] = f2b((v1-mu)*rs*w[tid+256] + bb[tid+256]);
}

// ---------------- layernorm over 512 cols of (in0+in1) (split-K partials) -> bf16 ----
__global__ __launch_bounds__(256) void layernorm2_k(const float* __restrict__ in0,
    const float* __restrict__ in1,
    const float* __restrict__ w, const float* __restrict__ bb, unsigned short* __restrict__ out){
  int row = blockIdx.x; int tid = threadIdx.x;
  const float* r0 = in0 + (size_t)row*DMODEL;
  const float* r1 = in1 + (size_t)row*DMODEL;
  float v0 = r0[tid] + r1[tid], v1 = r0[tid+256] + r1[tid+256];
  float s = v0+v1, sq = v0*v0+v1*v1;
  for (int m=32;m>=1;m>>=1){ s += __shfl_xor(s,m); sq += __shfl_xor(sq,m); }
  __shared__ float ws_[4], wq_[4];
  int wave = tid>>6, lane = tid&63;
  if (lane==0){ ws_[wave]=s; wq_[wave]=sq; }
  __syncthreads();
  s = ws_[0]+ws_[1]+ws_[2]+ws_[3]; sq = wq_[0]+wq_[1]+wq_[2]+wq_[3];
  float mu = s * (1.f/DMODEL);
  float var = sq * (1.f/DMODEL) - mu*mu;
  float rs = rsqrtf(var + 1e-5f);
  out[(size_t)row*DMODEL + tid]     = f2b((v0-mu)*rs*w[tid] + bb[tid]);
  out[(size_t)row*DMODEL + tid+256] = f2b((v1-mu)*rs*w[tid+256] + bb[tid+256]);
}

// ---------------- ff2 split-K reduce: out = p0+p1+p2+p3 + bias + resid (f32) -------
__global__ __launch_bounds__(256) void reduce4_k(const float* __restrict__ pa,
    const float* __restrict__ pb, const float* __restrict__ bias,
    const float* __restrict__ resid, float* __restrict__ out){
  const size_t MN4 = (size_t)NTOK*DMODEL/4;
  for (size_t i = (size_t)blockIdx.x*256 + threadIdx.x; i < MN4; i += (size_t)gridDim.x*256){
    float4 a0 = ((const float4*)pa)[i];
    float4 a1 = ((const float4*)pa)[i + MN4];
    float4 b0 = ((const float4*)pb)[i];
    float4 b1 = ((const float4*)pb)[i + MN4];
    float4 rv = ((const float4*)resid)[i];
    int col = (int)((i*4) & (DMODEL-1));
    const float4 bs = *(const float4*)(bias + col);
    float4 o;
    o.x = a0.x + a1.x + b0.x + b1.x + bs.x + rv.x;
    o.y = a0.y + a1.y + b0.y + b1.y + bs.y + rv.y;
    o.z = a0.z + a1.z + b0.z + b1.z + bs.z + rv.z;
    o.w = a0.w + a1.w + b0.w + b1.w + bs.w + rv.w;
    ((float4*)out)[i] = o;
  }
}

// ---------------- 256x256-tile bf16 GEMM, read-ahead-1 pipeline (3 barriers/K-tile) --
// C[M,N] (+)= A[M,K-slice] @ Bt[N,K-slice]^T, K-slice = [z*klen, (z+1)*klen).
// Fragment ds_reads for phase p+1 are issued during phase p; compiler inserts
// counted lgkmcnt before each MFMA cluster. Barrier ledger:
//  B1 (post-p2): all waves consumed kh0 -> safe to issue STG(t+2,kh0).
//  B2 (mid-p4, after vmcnt(8) drains (t+1,kh0) on every wave): next tile kh0
//     fully staged by ALL waves -> prefetch next-iter p1 fragments.
//  B3 (end, after vmcnt(4) drains (t+1,kh1)): kh1 consumed; next iter may stage.
// epi 0: f32 partial -> (z<2?outp:outp_hi) + (z&1)*M*N ; 1: bf16 gelu(v+bias) ; 3: bf16 plain.
__global__ __launch_bounds__(512, 2) void gemm256_k(const unsigned short* __restrict__ A,
    const unsigned short* __restrict__ Bt, void* __restrict__ outp, void* __restrict__ outp_hi,
    int M, int N, int K, int klen, int epi, const float* __restrict__ bias){
  __shared__ __align__(16) unsigned short As[32768];   // 64 KiB
  __shared__ __align__(16) unsigned short Bs[32768];   // 64 KiB
  const int tid = threadIdx.x;
  const int lane = tid & 63, wave = tid >> 6;
  const int wr = wave >> 2, wc = wave & 3;
  const int l15 = lane & 15, q = lane >> 4;
  // XCD-aware bijective swizzle within the z-slice (per-slice nwg % 8 == 0)
  int nbx = gridDim.x;
  int bid = blockIdx.y * nbx + blockIdx.x;
  int cpx = (nbx * gridDim.y) >> 3;
  int swz = (bid & 7) * cpx + (bid >> 3);
  int bn = swz % nbx, bm = swz / nbx;
  const int kstart = blockIdx.z * klen;
  const int NT = klen >> 6;
  const int j0 = tid, j1 = tid + 512;
  const int rr0 = j0 >> 2, rr1 = j1 >> 2;
  const int sc0 = (j0 & 3) ^ ((rr0 >> 1) & 3);
  const int sc1 = (j1 & 3) ^ ((rr1 >> 1) & 3);
  const unsigned short* a0 = A  + (size_t)(bm*256 + rr0)*K + kstart + sc0*8;
  const unsigned short* a1 = A  + (size_t)(bm*256 + rr1)*K + kstart + sc1*8;
  const unsigned short* b0 = Bt + (size_t)(bn*256 + rr0)*K + kstart + sc0*8;
  const unsigned short* b1 = Bt + (size_t)(bn*256 + rr1)*K + kstart + sc1*8;
  unsigned short* lA0 = As + j0*8;
  unsigned short* lA1 = As + j1*8;
  unsigned short* lB0 = Bs + j0*8;
  unsigned short* lB1 = Bs + j1*8;
#define STGA(t,kh) { const int go=(t)*64+(kh)*32, lo=((t)&1)*16384+(kh)*8192; \
  GLL16(a0+go, lA0+lo); GLL16(a1+go, lA1+lo); }
#define STGB(t,kh) { const int go=(t)*64+(kh)*32, lo=((t)&1)*16384+(kh)*8192; \
  GLL16(b0+go, lB0+lo); GLL16(b1+go, lB1+lo); }
  f32x4 acc[8][4];
  #pragma unroll
  for (int i=0;i<8;i++)
    #pragma unroll
    for (int j=0;j<4;j++) acc[i][j] = (f32x4){0.f,0.f,0.f,0.f};
  // prologue: tile0 fully + tile1 khalf0 (NT>=2 at all call sites).
  // vmcnt(4) drains tile0 entirely, leaving exactly the 4 (1,kh0) loads in
  // flight = steady-state loop entry condition.
  STGA(0,0); STGB(0,0); STGA(0,1); STGB(0,1);
  STGA(1,0); STGB(1,0);
  asm volatile("s_waitcnt vmcnt(4)" ::: "memory");
  __builtin_amdgcn_s_barrier();
  __builtin_amdgcn_sched_barrier(0);
  const int cOfs = (q ^ ((l15 >> 1) & 3)) * 8;
  const int arow = wr*128 + l15;
  const int brow = wc*64  + l15;
  short8 a0f[4], a1f[4], b0f[4], b1f[4];
  #pragma unroll
  for (int mi=0;mi<4;mi++) a0f[mi] = *(const short8*)(As + (arow + mi*16)*32 + cOfs);
  #pragma unroll
  for (int nt=0;nt<4;nt++) b0f[nt] = *(const short8*)(Bs + (brow + nt*16)*32 + cOfs);
  for (int t = 0; t < NT; ++t){
    const unsigned short* Ab  = As + (t & 1)*16384;
    const unsigned short* Bb  = Bs + (t & 1)*16384;
    const unsigned short* Abn = As + ((~t) & 1)*16384;
    const unsigned short* Bbn = Bs + ((~t) & 1)*16384;
    // ---- p1: MFMA kh0 m0-3 (a0f,b0f preloaded); issue kh0 m4-7 reads ----
    #pragma unroll
    for (int mi=0;mi<4;mi++) a1f[mi] = *(const short8*)(Ab + (arow + (4+mi)*16)*32 + cOfs);
    if (t+1 < NT) STGA(t+1,1);
    __builtin_amdgcn_s_setprio(1);
    #pragma unroll
    for (int mi=0;mi<4;mi++)
      #pragma unroll
      for (int nt=0;nt<4;nt++)
        acc[mi][nt] = __builtin_amdgcn_mfma_f32_16x16x32_bf16(a0f[mi], b0f[nt], acc[mi][nt], 0,0,0);
    __builtin_amdgcn_s_setprio(0);
    // ---- p2: MFMA kh0 m4-7; issue kh1 m0-3 + B kh1 reads ----
    #pragma unroll
    for (int mi=0;mi<4;mi++) a0f[mi] = *(const short8*)(Ab + 8192 + (arow + mi*16)*32 + cOfs);
    #pragma unroll
    for (int nt=0;nt<4;nt++) b1f[nt] = *(const short8*)(Bb + 8192 + (brow + nt*16)*32 + cOfs);
    if (t+1 < NT) STGB(t+1,1);
    __builtin_amdgcn_s_setprio(1);
    #pragma unroll
    for (int mi=0;mi<4;mi++)
      #pragma unroll
      for (int nt=0;nt<4;nt++)
        acc[4+mi][nt] = __builtin_amdgcn_mfma_f32_16x16x32_bf16(a1f[mi], b0f[nt], acc[4+mi][nt], 0,0,0);
    __builtin_amdgcn_s_setprio(0);
    __builtin_amdgcn_s_barrier();    // B1: kh0 consumed by all waves
    // ---- p3: MFMA kh1 m0-3; issue kh1 m4-7 reads; stage (t+2,kh0) A ----
    #pragma unroll
    for (int mi=0;mi<4;mi++) a1f[mi] = *(const short8*)(Ab + 8192 + (arow + (4+mi)*16)*32 + cOfs);
    if (t+2 < NT) STGA(t+2,0);
    __builtin_amdgcn_s_setprio(1);
    #pragma unroll
    for (int mi=0;mi<4;mi++)
      #pragma unroll
      for (int nt=0;nt<4;nt++)
        acc[mi][nt] = __builtin_amdgcn_mfma_f32_16x16x32_bf16(a0f[mi], b1f[nt], acc[mi][nt], 0,0,0);
    __builtin_amdgcn_s_setprio(0);
    // ---- p4: stage (t+2,kh0) B; drain (t+1,kh0); prefetch next p1; MFMA kh1 m4-7 ----
    if (t+2 < NT) STGB(t+2,0);
    if (t+2 < NT)      { asm volatile("s_waitcnt vmcnt(8)" ::: "memory"); }
    else if (t+1 < NT) { asm volatile("s_waitcnt vmcnt(4)" ::: "memory"); }
    __builtin_amdgcn_s_barrier();    // B2: next-tile kh0 staged by ALL waves
    __builtin_amdgcn_sched_barrier(0);
    if (t+1 < NT){
      #pragma unroll
      for (int mi=0;mi<4;mi++) a0f[mi] = *(const short8*)(Abn + (arow + mi*16)*32 + cOfs);
      #pragma unroll
      for (int nt=0;nt<4;nt++) b0f[nt] = *(const short8*)(Bbn + (brow + nt*16)*32 + cOfs);
    }
    __builtin_amdgcn_s_setprio(1);
    #pragma unroll
    for (int mi=0;mi<4;mi++)
      #pragma unroll
      for (int nt=0;nt<4;nt++)
        acc[4+mi][nt] = __builtin_amdgcn_mfma_f32_16x16x32_bf16(a1f[mi], b1f[nt], acc[4+mi][nt], 0,0,0);
    __builtin_amdgcn_s_setprio(0);
    if (t+2 < NT)      { asm volatile("s_waitcnt vmcnt(4)" ::: "memory"); }
    else if (t+1 < NT) { asm volatile("s_waitcnt vmcnt(0)" ::: "memory"); }
    __builtin_amdgcn_s_barrier();    // B3: kh1 consumed; (t+1,kh1) staged-drained
  }
#undef STGA
#undef STGB
  // ---- coalesced epilogue: per-wave 16x65-f32 LDS slab (overlays As), out ----
  float* cb = (float*)As + wave*1040;
  const int rbase = q*4;
  const int gr0t = bm*256 + wr*128;
  const int gc0 = bn*256 + wc*64;
  #pragma unroll
  for (int mt=0; mt<8; mt++){
    #pragma unroll
    for (int nt=0;nt<4;nt++)
      #pragma unroll
      for (int r=0;r<4;r++)
        cb[(rbase+r)*65 + nt*16 + l15] = acc[mt][nt][r];
    int gr0 = gr0t + mt*16;
    if (epi == 0){
      float* po = (float*)((blockIdx.z < 2) ? outp : outp_hi)
                + (size_t)(blockIdx.z & 1) * ((size_t)M * N);
      int r4 = lane >> 4, c0f = (lane & 15)*4;
      #pragma unroll
      for (int h=0; h<4; h++){
        int row = h*4 + r4;
        float4 v;
        v.x = cb[row*65 + c0f + 0];
        v.y = cb[row*65 + c0f + 1];
        v.z = cb[row*65 + c0f + 2];
        v.w = cb[row*65 + c0f + 3];
        *(float4*)(po + (size_t)(gr0+row)*N + gc0 + c0f) = v;
      }
    } else {
      int r8 = lane >> 3, c0 = (lane & 7)*8;
      #pragma unroll
      for (int h=0; h<2; h++){
        int row = h*8 + r8;
        float v[8];
        #pragma unroll
        for (int u=0;u<8;u++) v[u] = cb[row*65 + c0 + u];
        if (epi == 1){
          #pragma unroll
          for (int u=0;u<8;u++) v[u] = gelu_f(v[u] + bias[gc0 + c0 + u]);
        }
        *(uint4*)((unsigned short*)outp + (size_t)(gr0+row)*N + gc0 + c0) = pack8(v);
      }
    }
  }
}

// ---------------- dt/dA per (token, head), written for both directions ----------------
__global__ __launch_bounds__(256) void dt_k(const unsigned short* __restrict__ zx,
    const float* __restrict__ dt_bias, const float* __restrict__ A_log,
    float* __restrict__ dAb, float* __restrict__ dtb){
  int b = blockIdx.y;
  int t = blockIdx.x*16 + (threadIdx.x>>4);
  int h = threadIdx.x & 15;
  float raw = b2f(zx[((size_t)b*LSEQ + t)*NPAD + (DINNER+CONVDIM) + h]) + dt_bias[h];
  float dt = (raw > 20.f) ? raw : log1pf(expf(raw));
  float dA = expf(-expf(A_log[h]) * dt);
  size_t f = ((size_t)b*LSEQ + t)*NHEADS + h;
  size_t r = ((size_t)(BSZ+b)*LSEQ + (LSEQ-1-t))*NHEADS + h;
  dAb[f] = dA; dtb[f] = dt;
  dAb[r] = dA; dtb[r] = dt;
}

// ---------------- conv+silu for x-channels, BOTH directions, + z compaction ----------
__global__ __launch_bounds__(256) void conv_x_k(const unsigned short* __restrict__ zx,
    const float* __restrict__ conv_w, const float* __restrict__ conv_b,
    const float* __restrict__ dtb, unsigned short* __restrict__ dtxb,
    unsigned short* __restrict__ zcomp){
  int b = blockIdx.y;
  int t0blk = blockIdx.x * 32;
  int tid = threadIdx.x;
  int half = tid >> 7, cg = tid & 127;
  int c0 = cg * 8;
  int head = c0 >> 6;
  float wk[4][8], bias8[8];
  #pragma unroll
  for (int k=0;k<4;k++)
    #pragma unroll
    for (int j=0;j<8;j++) wk[k][j] = conv_w[k*CONVDIM + c0 + j];
  #pragma unroll
  for (int j=0;j<8;j++) bias8[j] = conv_b[c0 + j];
  __shared__ float sdtf[32][16], sdtb[32][16];
  for (int r = tid; r < 512; r += 256){
    int i = r >> 4, h = r & 15;
    sdtf[i][h] = dtb[((size_t)b*LSEQ + t0blk + i)*NHEADS + h];
    sdtb[i][h] = dtb[((size_t)(BSZ+b)*LSEQ + (LSEQ-1-(t0blk+i)))*NHEADS + h];
  }
  __syncthreads();
  int t0 = t0blk + half*16;
  float w0[8],w1[8],w2[8],w3[8];
  #pragma unroll
  for (int j=0;j<8;j++){ w1[j]=0.f; w2[j]=0.f; w3[j]=0.f; }
  for (int it=0; it<22; ++it){
    int t = t0 - 3 + it;
    #pragma unroll
    for (int j=0;j<8;j++){ w0[j]=w1[j]; w1[j]=w2[j]; w2[j]=w3[j]; }
    if (t >= 0 && t < LSEQ){
      uint4 xv = *(const uint4*)(zx + ((size_t)b*LSEQ + t)*NPAD + DINNER + c0);
      const unsigned short* xs = (const unsigned short*)&xv;
      #pragma unroll
      for (int j=0;j<8;j++) w3[j] = b2f(xs[j]);
      if (t >= t0 && t < t0+16){
        uint4 zv = *(const uint4*)(zx + ((size_t)b*LSEQ + t)*NPAD + c0);
        *(uint4*)(zcomp + ((size_t)b*LSEQ + t)*DINNER + c0) = zv;
      }
    } else {
      #pragma unroll
      for (int j=0;j<8;j++) w3[j] = 0.f;
    }
    if (t >= t0 && t < t0+16){
      float dtf = sdtf[t - t0blk][head];
      float v[8];
      #pragma unroll
      for (int j=0;j<8;j++){
        float a = bias8[j] + wk[0][j]*w0[j] + wk[1][j]*w1[j] + wk[2][j]*w2[j] + wk[3][j]*w3[j];
        v[j] = (a / (1.f + __expf(-a))) * dtf;
      }
      *(uint4*)(dtxb + ((size_t)b*LSEQ + t)*DINNER + c0) = pack8(v);
    }
    int tau = t - 3;
    if (tau >= t0 && tau < t0+16){
      float dtv = sdtb[tau - t0blk][head];
      float v[8];
      #pragma unroll
      for (int j=0;j<8;j++){
        float a = bias8[j] + wk[0][j]*w3[j] + wk[1][j]*w2[j] + wk[2][j]*w1[j] + wk[3][j]*w0[j];
        v[j] = (a / (1.f + __expf(-a))) * dtv;
      }
      *(uint4*)(dtxb + ((size_t)(BSZ+b)*LSEQ + (LSEQ-1-tau))*DINNER + c0) = pack8(v);
    }
  }
}

// ---------------- conv+silu for B/C channels, both directions ----------------
__global__ __launch_bounds__(256) void conv_bc_k(const unsigned short* __restrict__ zx,
    const float* __restrict__ conv_w, const float* __restrict__ conv_b,
    unsigned short* __restrict__ Bb, unsigned short* __restrict__ Cb){
  int b = blockIdx.y;
  int t0blk = blockIdx.x * 64;
  int tid = threadIdx.x;
  int slot = tid >> 4, cg = tid & 15;
  int c0 = cg*8;
  int ccol = DINNER + 1024 + c0;
  int cw = 1024 + c0;
  float wk[4][8], bias8[8];
  #pragma unroll
  for (int k=0;k<4;k++)
    #pragma unroll
    for (int j=0;j<8;j++) wk[k][j] = conv_w[k*CONVDIM + cw + j];
  #pragma unroll
  for (int j=0;j<8;j++) bias8[j] = conv_b[cw + j];
  int t0 = t0blk + slot*4;
  float w0[8],w1[8],w2[8],w3[8];
  #pragma unroll
  for (int j=0;j<8;j++){ w1[j]=0.f; w2[j]=0.f; w3[j]=0.f; }
  for (int it=0; it<10; ++it){
    int t = t0 - 3 + it;
    #pragma unroll
    for (int j=0;j<8;j++){ w0[j]=w1[j]; w1[j]=w2[j]; w2[j]=w3[j]; }
    if (t >= 0 && t < LSEQ){
      uint4 xv = *(const uint4*)(zx + ((size_t)b*LSEQ + t)*NPAD + ccol);
      const unsigned short* xs = (const unsigned short*)&xv;
      #pragma unroll
      for (int j=0;j<8;j++) w3[j] = b2f(xs[j]);
    } else {
      #pragma unroll
      for (int j=0;j<8;j++) w3[j] = 0.f;
    }
    if (t >= t0 && t < t0+4){
      float v[8];
      #pragma unroll
      for (int j=0;j<8;j++){
        float a = bias8[j] + wk[0][j]*w0[j] + wk[1][j]*w1[j] + wk[2][j]*w2[j] + wk[3][j]*w3[j];
        v[j] = a / (1.f + __expf(-a));
      }
      size_t tok = (size_t)b*LSEQ + t;
      if (c0 < 64) *(uint4*)(Bb + tok*DSTATE + c0)      = pack8(v);
      else         *(uint4*)(Cb + tok*DSTATE + (c0-64)) = pack8(v);
    }
    int tau = t - 3;
    if (tau >= t0 && tau < t0+4){
      float v[8];
      #pragma unroll
      for (int j=0;j<8;j++){
        float a = bias8[j] + wk[0][j]*w3[j] + wk[1][j]*w2[j] + wk[2][j]*w1[j] + wk[3][j]*w0[j];
        v[j] = a / (1.f + __expf(-a));
      }
      size_t tok = (size_t)(BSZ+b)*LSEQ + (LSEQ-1-tau);
      if (c0 < 64) *(uint4*)(Bb + tok*DSTATE + c0)      = pack8(v);
      else         *(uint4*)(Cb + tok*DSTATE + (c0-64)) = pack8(v);
    }
  }
}

// ---- 64x64x64 bf16 GEMM on one wave, with optional chunk-XOR swizzle per operand.
// Swizzled layout: element (r, c) lives at r*72 + ((c>>3) ^ ((r>>3)&7))*8 + (c&7).
template<int SA, int SB>
__device__ inline void gemm64s(const unsigned short* Ab, const unsigned short* Bb_,
                               int l15, int q, f32x4 acc[4][4]){
  #pragma unroll
  for (int ks=0; ks<2; ks++){
    short8 af[4], bf4[4];
    #pragma unroll
    for (int mt=0;mt<4;mt++){
      int r = mt*16 + l15;
      int c = ks*4 + q; if (SA) c ^= (r>>3)&7;
      af[mt] = *(const short8*)(Ab + r*72 + c*8);
    }
    #pragma unroll
    for (int nt=0;nt<4;nt++){
      int r = nt*16 + l15;
      int c = ks*4 + q; if (SB) c ^= (r>>3)&7;
      bf4[nt] = *(const short8*)(Bb_ + r*72 + c*8);
    }
    #pragma unroll
    for (int mt=0;mt<4;mt++)
      #pragma unroll
      for (int nt=0;nt<4;nt++)
        acc[mt][nt] = __builtin_amdgcn_mfma_f32_16x16x32_bf16(af[mt], bf4[nt], acc[mt][nt], 0,0,0);
  }
}
__device__ inline void gemm64(const unsigned short* Ab, const unsigned short* Bb_,
                              int l15, int q, f32x4 acc[4][4]){
  gemm64s<0,0>(Ab, Bb_, l15, q, acc);
}

// ---------------- SSD pass 1: per chunk: Y_intra (masked attention form) + local state G ----
// Transpose-fills (S3 dtx, S2 decay-B) and the masked-P fill use the chunk-XOR
// swizzle (16-way / 4-way bank conflicts otherwise); matching gemm64s reads.
__global__ __launch_bounds__(64) void ssd1_k(const float* __restrict__ dAb,
    const unsigned short* __restrict__ dtxb, const unsigned short* __restrict__ Bb,
    const unsigned short* __restrict__ Cb,
    unsigned short* __restrict__ y0, unsigned short* __restrict__ y1,
    unsigned short* __restrict__ hbuf, float* __restrict__ Pch, float* __restrict__ ebuf){
  int ch = blockIdx.x, h = blockIdx.y, z = blockIdx.z;
  int d = z >> 1, b = z & 1;
  int lane = threadIdx.x;
  int l15 = lane & 15, q = lane >> 4;
  int tr = lane >> 3, cb8 = (lane & 7)*8;
  int m7 = lane & 7;                       // = (cb8+j)>>3 for j in [0,8)
  size_t tokb = (size_t)z*LSEQ + (size_t)ch*64;
  size_t zhc = ((size_t)z*NHEADS + h)*NCH + ch;
  __shared__ __align__(16) unsigned short S1[64*72];
  __shared__ __align__(16) unsigned short S2[64*72];
  __shared__ __align__(16) unsigned short S3[64*72];
  __shared__ float Lb[64];
  float L = fmaxf(logf(dAb[(tokb + lane)*NHEADS + h]), -60.f);
  #pragma unroll
  for (int off=1; off<64; off<<=1){
    float v = __shfl_up(L, off);
    if (lane >= off) L += v;
  }
  Lb[lane] = L;
  float e = __expf(L);
  ebuf[zhc*64 + lane] = e;
  if (lane == 63) Pch[zhc] = e;
  for (int i=0;i<8;i++){
    int t = i*8 + tr;
    *(uint4*)&S1[t*72 + cb8] = *(const uint4*)(Cb + (tokb+t)*DSTATE + cb8);
    *(uint4*)&S2[t*72 + cb8] = *(const uint4*)(Bb + (tokb+t)*DSTATE + cb8);
    uint4 xv = *(const uint4*)(dtxb + (tokb+t)*DINNER + (size_t)h*64 + cb8);
    const unsigned short* xs = (const unsigned short*)&xv;
    int csw = ((i ^ m7) << 3) + tr;        // swizzled column for token t
    #pragma unroll
    for (int j=0;j<8;j++) S3[(cb8+j)*72 + csw] = xs[j];
  }
  f32x4 sa[4][4];
  for (int i=0;i<4;i++) for (int j=0;j<4;j++) sa[i][j] = (f32x4){0.f,0.f,0.f,0.f};
  gemm64s<0,0>(S1, S2, l15, q, sa);
  float Lsv[4];
  #pragma unroll
  for (int nt=0;nt<4;nt++) Lsv[nt] = Lb[nt*16 + l15];
  int sch = l15 >> 3, sin = l15 & 7;       // s-chunk parity / within-chunk
  #pragma unroll
  for (int mt=0;mt<4;mt++){
    #pragma unroll
    for (int r=0;r<4;r++){
      int t = mt*16 + q*4 + r;
      int trow = (t>>3)&7;
      float Lt = Lb[t];
      #pragma unroll
      for (int nt=0;nt<4;nt++){
        int s = nt*16 + l15;
        float v = (t >= s) ? __expf(Lt - Lsv[nt]) * sa[mt][nt][r] : 0.f;
        S1[t*72 + (((nt*2 + sch) ^ trow)<<3) + sin] = f2b(v);   // swizzled P
      }
    }
  }
  f32x4 ya[4][4];
  for (int i=0;i<4;i++) for (int j=0;j<4;j++) ya[i][j] = (f32x4){0.f,0.f,0.f,0.f};
  gemm64s<1,1>(S1, S3, l15, q, ya);
  #pragma unroll
  for (int mt=0;mt<4;mt++)
    #pragma unroll
    for (int pt=0;pt<4;pt++)
      #pragma unroll
      for (int r=0;r<4;r++)
        S2[(mt*16+q*4+r)*72 + pt*16 + l15] = f2b(ya[mt][pt][r]);
  unsigned short* yb = d ? y1 : y0;
  for (int i=0;i<8;i++){
    int t = i*8 + tr; int g = ch*64 + t;
    int tph = d ? (LSEQ-1-g) : g;
    *(uint4*)(yb + ((size_t)b*LSEQ + tph)*DINNER + (size_t)h*64 + cb8) = *(uint4*)&S2[t*72 + cb8];
  }
  float L63 = Lb[63];
  for (int i=0;i<8;i++){
    int s = i*8 + tr;
    float w = __expf(L63 - Lb[s]);
    uint4 bv = *(const uint4*)(Bb + (tokb+s)*DSTATE + cb8);
    const unsigned short* bs = (const unsigned short*)&bv;
    int csw = ((i ^ m7) << 3) + tr;        // swizzled column for token s
    #pragma unroll
    for (int j=0;j<8;j++) S2[(cb8+j)*72 + csw] = f2b(w * b2f(bs[j]));
  }
  f32x4 ga[4][4];
  for (int i=0;i<4;i++) for (int j=0;j<4;j++) ga[i][j] = (f32x4){0.f,0.f,0.f,0.f};
  gemm64s<1,1>(S3, S2, l15, q, ga);
  #pragma unroll
  for (int pt=0;pt<4;pt++)
    #pragma unroll
    for (int nt=0;nt<4;nt++)
      #pragma unroll
      for (int r=0;r<4;r++)
        S1[(pt*16+q*4+r)*72 + nt*16 + l15] = f2b(ga[pt][nt][r]);
  for (int i=0;i<8;i++){
    int p = i*8 + tr;
    *(uint4*)(hbuf + zhc*4096 + (size_t)p*64 + cb8) = *(uint4*)&S1[p*72 + cb8];
  }
}

// ---------------- combine chunk states, IN PLACE (4-way over state dim, prefetched) ----
__global__ __launch_bounds__(256) void comb_k(unsigned short* __restrict__ hbuf,
    const float* __restrict__ Pch){
  int u = blockIdx.x; int tid = threadIdx.x;
  int kb = blockIdx.y * 4;
  size_t base0 = ((size_t)u*NCH)*4096;
  float hreg[4];
  unsigned short ccur[4], cnxt[4] = {0,0,0,0};
  #pragma unroll
  for (int k=0;k<4;k++){ hreg[k]=0.f; ccur[k] = hbuf[base0 + tid + (size_t)(kb+k)*256]; }
  float Pc = Pch[(size_t)u*NCH], Pn = 0.f;
  for (int ch=0; ch<NCH; ch++){
    size_t base = base0 + (size_t)ch*4096;
    if (ch+1 < NCH){
      size_t bnx = base + 4096;
      #pragma unroll
      for (int k=0;k<4;k++) cnxt[k] = hbuf[bnx + tid + (size_t)(kb+k)*256];
      Pn = Pch[(size_t)u*NCH + ch + 1];
    }
    #pragma unroll
    for (int k=0;k<4;k++){
      hbuf[base + tid + (size_t)(kb+k)*256] = f2b(hreg[k]);
      hreg[k] = hreg[k]*Pc + b2f(ccur[k]);
    }
    #pragma unroll
    for (int k=0;k<4;k++) ccur[k] = cnxt[k];
    Pc = Pn;
  }
}

// ---------------- SSD pass 2: Y += diag(e) C h_in^T + D*xh ----------------
__global__ __launch_bounds__(64) void ssd2_k(const unsigned short* __restrict__ Cb,
    const unsigned short* __restrict__ hbuf, const unsigned short* __restrict__ dtxb,
    const float* __restrict__ dtb, const float* __restrict__ ebuf, const float* __restrict__ Dh,
    unsigned short* __restrict__ y0, unsigned short* __restrict__ y1){
  int ch = blockIdx.x, h = blockIdx.y, z = blockIdx.z;
  int d = z >> 1, b = z & 1;
  int lane = threadIdx.x;
  int l15 = lane & 15, q = lane >> 4;
  int tr = lane >> 3, cb8 = (lane & 7)*8;
  size_t tokb = (size_t)z*LSEQ + (size_t)ch*64;
  size_t zhc = ((size_t)z*NHEADS + h)*NCH + ch;
  __shared__ __align__(16) unsigned short S1[64*72];
  __shared__ __align__(16) unsigned short S2[64*72];
  __shared__ __align__(16) unsigned short S3[64*72];
  __shared__ float eb2[64], dti[64];
  eb2[lane] = ebuf[zhc*64 + lane];
  dti[lane] = 1.f / dtb[(tokb + lane)*NHEADS + h];
  float Dv = Dh[h];
  for (int i=0;i<8;i++){
    int t = i*8 + tr;
    *(uint4*)&S1[t*72 + cb8] = *(const uint4*)(Cb + (tokb+t)*DSTATE + cb8);
    *(uint4*)&S2[t*72 + cb8] = *(const uint4*)(hbuf + zhc*4096 + (size_t)t*64 + cb8);
  }
  f32x4 acc[4][4];
  for (int i=0;i<4;i++) for (int j=0;j<4;j++) acc[i][j] = (f32x4){0.f,0.f,0.f,0.f};
  gemm64(S1, S2, l15, q, acc);
  unsigned short* yb = d ? y1 : y0;
  #pragma unroll
  for (int mt=0;mt<4;mt++){
    #pragma unroll
    for (int r=0;r<4;r++){
      int t = mt*16 + q*4 + r; int g = ch*64 + t;
      int tph = d ? (LSEQ-1-g) : g;
      size_t rowb = ((size_t)b*LSEQ + tph)*DINNER + (size_t)h*64;
      size_t dxb_ = (tokb + t)*DINNER + (size_t)h*64;
      float et = eb2[t], di = dti[t];
      #pragma unroll
      for (int pt=0;pt<4;pt++){
        int p = pt*16 + l15;
        float v = acc[mt][pt][r]*et + b2f(yb[rowb + p]) + Dv * b2f(dtxb[dxb_ + p]) * di;
        S3[t*72 + p] = f2b(v);
      }
    }
  }
  for (int i=0;i<8;i++){
    int t = i*8 + tr; int g = ch*64 + t;
    int tph = d ? (LSEQ-1-g) : g;
    *(uint4*)(yb + ((size_t)b*LSEQ + tph)*DINNER + (size_t)h*64 + cb8) = *(uint4*)&S3[t*72 + cb8];
  }
}

// ---------------- gate: g=y*silu(z), per-dir rmsnorm, sum, ->bf16 ----------------
__global__ __launch_bounds__(256) void gate_k(const unsigned short* __restrict__ y0,
    const unsigned short* __restrict__ y1, const unsigned short* __restrict__ zcomp,
    const float* __restrict__ mnw, unsigned short* __restrict__ gsum){
  int tok = blockIdx.x; int tid = threadIdx.x;
  __shared__ float g0s[DINNER], g1s[DINNER];
  float ss0 = 0.f, ss1 = 0.f;
  for (int i=0;i<4;i++){
    int c = tid + i*256;
    float z = b2f(zcomp[(size_t)tok*DINNER + c]);
    float sz = z / (1.f + __expf(-z));
    float g0 = b2f(y0[(size_t)tok*DINNER + c]) * sz;
    float g1 = b2f(y1[(size_t)tok*DINNER + c]) * sz;
    g0s[c] = g0; g1s[c] = g1;
    ss0 += g0*g0; ss1 += g1*g1;
  }
  for (int m=32;m>=1;m>>=1){ ss0 += __shfl_xor(ss0,m); ss1 += __shfl_xor(ss1,m); }
  __shared__ float w0[4], w1[4];
  int wave = tid>>6, lane = tid&63;
  if (lane==0){ w0[wave]=ss0; w1[wave]=ss1; }
  __syncthreads();
  ss0 = w0[0]+w0[1]+w0[2]+w0[3];
  ss1 = w1[0]+w1[1]+w1[2]+w1[3];
  float r0 = rsqrtf(ss0*(1.f/DINNER) + 1e-5f);
  float r1 = rsqrtf(ss1*(1.f/DINNER) + 1e-5f);
  for (int i=0;i<4;i++){
    int c = tid + i*256;
    gsum[(size_t)tok*DINNER + c] = f2b((g0s[c]*r0 + g1s[c]*r1) * mnw[c]);
  }
}

extern "C" void kernel_launch(void* const* d_in, const int* in_sizes, int n_in,
                              void* d_out, int out_size, void* d_ws, size_t ws_size,
                              hipStream_t stream){
  const float* x       = (const float*)d_in[0];
  const float* nin_w   = (const float*)d_in[1];
  const float* nin_b   = (const float*)d_in[2];
  const float* nout_w  = (const float*)d_in[3];
  const float* nout_b  = (const float*)d_in[4];
  const float* in_w    = (const float*)d_in[5];
  const float* conv_w  = (const float*)d_in[6];
  const float* conv_b  = (const float*)d_in[7];
  const float* dt_bias = (const float*)d_in[8];
  const float* A_log   = (const float*)d_in[9];
  const float* D_h     = (const float*)d_in[10];
  const float* mnorm_w = (const float*)d_in[11];
  const float* out_w   = (const float*)d_in[12];
  const float* ff_w1   = (const float*)d_in[13];
  const float* ff_b1   = (const float*)d_in[14];
  const float* ff_w2   = (const float*)d_in[15];
  const float* ff_b2   = (const float*)d_in[16];
  float* out = (float*)d_out;

  char* ws = (char*)d_ws;
  size_t off = 0;
  auto alloc = [&](size_t bytes)->char*{
    char* p = ws + off; off = (off + bytes + 255) & ~(size_t)255; return p; };
  unsigned short* xn_bf = (unsigned short*)alloc((size_t)NTOK*DMODEL*2);
  unsigned short* in_wT = (unsigned short*)alloc((size_t)NPAD*DMODEL*2);
  unsigned short* out_wT= (unsigned short*)alloc((size_t)DMODEL*DINNER*2);
  unsigned short* w1T   = (unsigned short*)alloc((size_t)2048*DMODEL*2);
  unsigned short* w2T   = (unsigned short*)alloc((size_t)DMODEL*2048*2);
  unsigned short* zx    = (unsigned short*)alloc((size_t)NTOK*NPAD*2);      // 37.7 MB
  unsigned short* zcomp = (unsigned short*)alloc((size_t)NTOK*DINNER*2);    // 16.8 MB
  float*          dAb   = (float*)alloc((size_t)2*NTOK*NHEADS*4);
  float*          dtb   = (float*)alloc((size_t)2*NTOK*NHEADS*4);
  unsigned short* Bb    = (unsigned short*)alloc((size_t)2*NTOK*DSTATE*2);
  unsigned short* Cb    = (unsigned short*)alloc((size_t)2*NTOK*DSTATE*2);
  unsigned short* dtxb  = (unsigned short*)alloc((size_t)2*NTOK*DINNER*2);  // 33.6 MB
  unsigned short* y0    = (unsigned short*)alloc((size_t)NTOK*DINNER*2);    // 16.8 MB
  unsigned short* y1    = (unsigned short*)alloc((size_t)NTOK*DINNER*2);    // 16.8 MB (contiguous after y0)
  float*          Pch   = (float*)alloc((size_t)64*NCH*4);
  float*          ebuf  = (float*)alloc((size_t)64*NCH*64*4);               // 1.05 MB
  size_t need = off;
  if (need > ws_size) return;  // fail absmax cleanly instead of faulting

  // aliases into sequentially-dead regions (stream order makes each safe):
  unsigned short* hbuf  = zx;        // chunk states; zx dead after conv kernels
  unsigned short* gsum  = dtxb;      // dtxb dead after ssd2_k
  unsigned short* m_bf  = y0;        // y0 dead after gate_k
  unsigned short* h1    = zx;        // ff1 out; zx region free after layernorm2 consumed mp
  float* mp   = (float*)zx;          // out_proj split-K partials S=2 (33.6 MB <= 37.7)
  float* fp01 = (float*)dtxb;        // ff2 partials z=0,1 (gsum dead after out_proj)
  float* fp23 = (float*)y0;          // ff2 partials z=2,3 (y0+y1 contiguous, dead after ff1/gate)

  // weight transposes -> bf16 [N][K]
  wconv_t<<<dim3(NPAD/32,   DMODEL/32), 256, 0, stream>>>(in_w,  in_wT,  DMODEL, DPROJ,  NPAD);
  wconv_t<<<dim3(DMODEL/32, DINNER/32), 256, 0, stream>>>(out_w, out_wT, DINNER, DMODEL, DMODEL);
  wconv_t<<<dim3(2048/32,   DMODEL/32), 256, 0, stream>>>(ff_w1, w1T,    DMODEL, 2048,   2048);
  wconv_t<<<dim3(DMODEL/32, 2048/32),   256, 0, stream>>>(ff_w2, w2T,    2048,   DMODEL, DMODEL);
  // LN in -> bf16
  layernorm_k<<<NTOK, 256, 0, stream>>>(x, nin_w, nin_b, xn_bf);
  // in_proj (shared between directions) -> bf16 zx   [256^2 read-ahead pipeline]
  gemm256_k<<<dim3(NPAD/256, NTOK/256, 1), 512, 0, stream>>>(xn_bf, in_wT, zx, nullptr, NTOK, NPAD, DMODEL, DMODEL, 3, nullptr);
  // dt/dA then conv (both directions from one pass) + z compaction
  dt_k<<<dim3(LSEQ/16, BSZ), 256, 0, stream>>>(zx, dt_bias, A_log, dAb, dtb);
  conv_x_k<<<dim3(LSEQ/32, BSZ), 256, 0, stream>>>(zx, conv_w, conv_b, dtb, dtxb, zcomp);
  conv_bc_k<<<dim3(LSEQ/64, BSZ), 256, 0, stream>>>(zx, conv_w, conv_b, Bb, Cb);
  // chunked SSD: intra-chunk (MFMA) -> combine -> inter-chunk (MFMA)
  ssd1_k<<<dim3(NCH, NHEADS, 2*BSZ), 64, 0, stream>>>(dAb, dtxb, Bb, Cb, y0, y1, hbuf, Pch, ebuf);
  comb_k<<<dim3(64, 4), 256, 0, stream>>>(hbuf, Pch);
  ssd2_k<<<dim3(NCH, NHEADS, 2*BSZ), 64, 0, stream>>>(Cb, hbuf, dtxb, dtb, ebuf, D_h, y0, y1);
  // gate + per-dir rmsnorm + sum (linearity: single out_proj GEMM)
  gate_k<<<NTOK, 256, 0, stream>>>(y0, y1, zcomp, mnorm_w, gsum);
  // out_proj: split-K=2 -> f32 partials mp[2]
  gemm256_k<<<dim3(DMODEL/256, NTOK/256, 2), 512, 0, stream>>>(gsum, out_wT, mp, nullptr, NTOK, DMODEL, DINNER, 512, 0, nullptr);
  // LN out over (mp0+mp1) -> bf16
  layernorm2_k<<<NTOK, 256, 0, stream>>>(mp, mp + (size_t)NTOK*DMODEL, nout_w, nout_b, m_bf);
  // ff1 + gelu -> bf16
  gemm256_k<<<dim3(2048/256, NTOK/256, 1), 512, 0, stream>>>(m_bf, w1T, h1, nullptr, NTOK, 2048, DMODEL, DMODEL, 1, ff_b1);
  // ff2: split-K=4 -> f32 partials fp01[2], fp23[2]
  gemm256_k<<<dim3(DMODEL/256, NTOK/256, 4), 512, 0, stream>>>(h1, w2T, fp01, fp23, NTOK, DMODEL, 2048, 512, 0, nullptr);
  // reduce partials + bias + residual -> f32 out
  reduce4_k<<<2048, 256, 0, stream>>>(fp01, fp23, ff_b2, x, out);
}

// Round 6
// 398.712 us; speedup vs baseline: 1.0126x; 1.0126x over previous
//
#include <hip/hip_runtime.h>
#include <hip/hip_bf16.h>

#define LSEQ 4096
#define BSZ 2
#define DMODEL 512
#define DINNER 1024
#define DSTATE 64
#define NHEADS 16
#define CONVDIM 1152
#define DPROJ 2192
#define NPAD 2304
#define NTOK (BSZ*LSEQ)
#define NCH 64   /* 64-token chunks */

typedef __attribute__((ext_vector_type(8))) short short8;
typedef __attribute__((ext_vector_type(4))) float f32x4;

__device__ inline unsigned short f2b(float v){
  unsigned int u = __builtin_bit_cast(unsigned int, v);
  unsigned int r = (u + 0x7FFFu + ((u >> 16) & 1u)) >> 16;
  return (unsigned short)r;
}
__device__ inline float b2f(unsigned short u){
  unsigned int x = ((unsigned int)u) << 16;
  return __builtin_bit_cast(float, x);
}
__device__ inline uint4 pack8(const float* v){
  uint4 pk;
  pk.x = (unsigned)f2b(v[0]) | ((unsigned)f2b(v[1])<<16);
  pk.y = (unsigned)f2b(v[2]) | ((unsigned)f2b(v[3])<<16);
  pk.z = (unsigned)f2b(v[4]) | ((unsigned)f2b(v[5])<<16);
  pk.w = (unsigned)f2b(v[6]) | ((unsigned)f2b(v[7])<<16);
  return pk;
}
// tanh-form gelu (max abs err ~3e-4 vs exact erf form; far below bf16 noise here)
__device__ inline float gelu_f(float x){
  float x2 = x*x;
  float u = x*(0.7978845608f + 0.0356774081f*x2);
  float au = fabsf(u);
  float z = __expf(-2.f*au);
  float t = (1.f - z)/(1.f + z);
  t = (u >= 0.f) ? t : -t;
  return 0.5f*x*(1.f + t);
}

#define GLL16(gp, lp) __builtin_amdgcn_global_load_lds( \
    (const __attribute__((address_space(1))) unsigned int*)(gp), \
    (__attribute__((address_space(3))) unsigned int*)(lp), 16, 0, 0)

// ---------------- weight transpose + f32->bf16 (src [K][Nsrc] -> dst [Npad][K]) ----
__global__ __launch_bounds__(256) void wconv_t(const float* __restrict__ src,
    unsigned short* __restrict__ dst, int K, int Nsrc, int Npad){
  __shared__ float t[32][33];
  int n0 = blockIdx.x*32, k0 = blockIdx.y*32;
  int tx = threadIdx.x & 31, ty = threadIdx.x >> 5;
  for (int i=0;i<4;i++){
    int k = k0 + ty + i*8; int n = n0 + tx;
    t[ty + i*8][tx] = (n < Nsrc) ? src[(size_t)k*Nsrc + n] : 0.f;
  }
  __syncthreads();
  for (int i=0;i<4;i++){
    int n = n0 + ty + i*8; int k = k0 + tx;
    if (n < Npad) dst[(size_t)n*K + k] = f2b(t[tx][ty + i*8]);
  }
}

// ---------------- layernorm over 512 cols (f32 in) -> bf16 ----------------
__global__ __launch_bounds__(256) void layernorm_k(const float* __restrict__ in,
    const float* __restrict__ w, const float* __restrict__ bb, unsigned short* __restrict__ out){
  int row = blockIdx.x; int tid = threadIdx.x;
  const float* r = in + (size_t)row*DMODEL;
  float v0 = r[tid], v1 = r[tid+256];
  float s = v0+v1, sq = v0*v0+v1*v1;
  for (int m=32;m>=1;m>>=1){ s += __shfl_xor(s,m); sq += __shfl_xor(sq,m); }
  __shared__ float ws_[4], wq_[4];
  int wave = tid>>6, lane = tid&63;
  if (lane==0){ ws_[wave]=s; wq_[wave]=sq; }
  __syncthreads();
  s = ws_[0]+ws_[1]+ws_[2]+ws_[3]; sq = wq_[0]+wq_[1]+wq_[2]+wq_[3];
  float mu = s * (1.f/DMODEL);
  float var = sq * (1.f/DMODEL) - mu*mu;
  float rs = rsqrtf(var + 1e-5f);
  out[(size_t)row*DMODEL + tid]     = f2b((v0-mu)*rs*w[tid] + bb[tid]);
  out[(size_t)row*DMODEL + tid+256] = f2b((v1-mu)*rs*w[tid+256] + bb[tid+256]);
}

// ---------------- layernorm over 512 cols of (p0+p1+p2+p3) (split-K partials) -> bf16 ----
__global__ __launch_bounds__(256) void layernorm4_k(const float* __restrict__ in0,
    const float* __restrict__ in1, const float* __restrict__ in2, const float* __restrict__ in3,
    const float* __restrict__ w, const float* __restrict__ bb, unsigned short* __restrict__ out){
  int row = blockIdx.x; int tid = threadIdx.x;
  size_t o = (size_t)row*DMODEL;
  float v0 = in0[o+tid] + in1[o+tid] + in2[o+tid] + in3[o+tid];
  float v1 = in0[o+tid+256] + in1[o+tid+256] + in2[o+tid+256] + in3[o+tid+256];
  float s = v0+v1, sq = v0*v0+v1*v1;
  for (int m=32;m>=1;m>>=1){ s += __shfl_xor(s,m); sq += __shfl_xor(sq,m); }
  __shared__ float ws_[4], wq_[4];
  int wave = tid>>6, lane = tid&63;
  if (lane==0){ ws_[wave]=s; wq_[wave]=sq; }
  __syncthreads();
  s = ws_[0]+ws_[1]+ws_[2]+ws_[3]; sq = wq_[0]+wq_[1]+wq_[2]+wq_[3];
  float mu = s * (1.f/DMODEL);
  float var = sq * (1.f/DMODEL) - mu*mu;
  float rs = rsqrtf(var + 1e-5f);
  out[o + tid]     = f2b((v0-mu)*rs*w[tid] + bb[tid]);
  out[o + tid+256] = f2b((v1-mu)*rs*w[tid+256] + bb[tid+256]);
}

// ---------------- ff2 split-K reduce: out = p0+p1+p2+p3 + bias + resid (f32) -------
__global__ __launch_bounds__(256) void reduce4_k(const float* __restrict__ pa,
    const float* __restrict__ pb, const float* __restrict__ bias,
    const float* __restrict__ resid, float* __restrict__ out){
  const size_t MN4 = (size_t)NTOK*DMODEL/4;
  for (size_t i = (size_t)blockIdx.x*256 + threadIdx.x; i < MN4; i += (size_t)gridDim.x*256){
    float4 a0 = ((const float4*)pa)[i];
    float4 a1 = ((const float4*)pa)[i + MN4];
    float4 b0 = ((const float4*)pb)[i];
    float4 b1 = ((const float4*)pb)[i + MN4];
    float4 rv = ((const float4*)resid)[i];
    int col = (int)((i*4) & (DMODEL-1));
    const float4 bs = *(const float4*)(bias + col);
    float4 o;
    o.x = a0.x + a1.x + b0.x + b1.x + bs.x + rv.x;
    o.y = a0.y + a1.y + b0.y + b1.y + bs.y + rv.y;
    o.z = a0.z + a1.z + b0.z + b1.z + bs.z + rv.z;
    o.w = a0.w + a1.w + b0.w + b1.w + bs.w + rv.w;
    ((float4*)out)[i] = o;
  }
}

// ---------------- 128x256-tile bf16 GEMM, BK=32 dbuf, 2 blocks/CU (TLP regime) ------
// C[M,N] (+)= A[M,K-slice] @ Bt[N,K-slice]^T, K-slice = [z*klen, (z+1)*klen).
// Design: 48 KiB LDS + <=128 VGPR (launch_bounds 512,4) so TWO 8-wave blocks
// co-reside per CU; co-resident block hides this block's stage/barrier stalls
// (m97/m114 regime) instead of intra-block pipelining (r4/r5 nulls at 1 blk/CU).
// Counted vmcnt(3) keeps next tile's loads in flight across the barrier;
// 2 barriers/K-tile. Chunk-XOR swizzle on LDS reads mirrored into the
// global_load_lds SOURCE (linear dest). Requirements: M%128==0, N%256==0,
// klen%32==0, NT>=2, per-slice nwg%8==0.
// epi 0: f32 partial -> (z<2?outp:outp_hi) + (z&1)*M*N ; 1: bf16 gelu(v+bias) ; 3: bf16 plain.
__global__ __launch_bounds__(512, 4) void gemm128_k(const unsigned short* __restrict__ A,
    const unsigned short* __restrict__ Bt, void* __restrict__ outp, void* __restrict__ outp_hi,
    int M, int N, int K, int klen, int epi, const float* __restrict__ bias){
  __shared__ __align__(16) unsigned short sm[24576];   // 48 KiB
  unsigned short* As = sm;           // [2][128][32]
  unsigned short* Bs = sm + 8192;    // [2][256][32]
  const int tid = threadIdx.x;
  const int lane = tid & 63, wave = tid >> 6;
  const int wr = wave >> 2, wc = wave & 3;   // 2 M-groups x 4 N-groups, 64x64/wave
  const int l15 = lane & 15, q = lane >> 4;
  // XCD-aware bijective swizzle within the z-slice (per-slice nwg % 8 == 0)
  int nbx = gridDim.x;
  int bid = blockIdx.y * nbx + blockIdx.x;
  int cpx = (nbx * gridDim.y) >> 3;
  int swz = (bid & 7) * cpx + (bid >> 3);
  int bn = swz % nbx, bm = swz / nbx;
  const int kstart = blockIdx.z * klen;
  const int NT = klen >> 5;                  // BK = 32
  // staging: A tile 128x32 = 512 chunks (1/thread); B tile 256x32 = 1024 (2/thread)
  const int ra  = tid >> 2;
  const int sca = (tid & 3) ^ ((ra >> 1) & 3);
  const int jb1 = tid + 512;
  const int rb1 = jb1 >> 2;
  const int scb1 = (jb1 & 3) ^ ((rb1 >> 1) & 3);
  const unsigned short* ga  = A  + (size_t)(bm*128 + ra )*K + kstart + sca*8;
  const unsigned short* gb0 = Bt + (size_t)(bn*256 + ra )*K + kstart + sca*8;
  const unsigned short* gb1 = Bt + (size_t)(bn*256 + rb1)*K + kstart + scb1*8;
  unsigned short* lAa = As + tid*8;
  unsigned short* lB0 = Bs + tid*8;
  unsigned short* lB1 = Bs + jb1*8;
#define STG(t) { const int go=(t)*32, loa=((t)&1)*4096, lob=((t)&1)*8192; \
  GLL16(ga+go, lAa+loa); GLL16(gb0+go, lB0+lob); GLL16(gb1+go, lB1+lob); }
  f32x4 acc[4][4];
  #pragma unroll
  for (int i=0;i<4;i++)
    #pragma unroll
    for (int j=0;j<4;j++) acc[i][j] = (f32x4){0.f,0.f,0.f,0.f};
  STG(0); STG(1);                            // 6 loads/thread in flight
  const int cOfs = (q ^ ((l15 >> 1) & 3)) * 8;
  const int arow = wr*64 + l15;
  const int brow = wc*64 + l15;
  for (int t = 0; t < NT; ++t){
    if (t+1 < NT) { asm volatile("s_waitcnt vmcnt(3)" ::: "memory"); }
    else          { asm volatile("s_waitcnt vmcnt(0)" ::: "memory"); }
    __builtin_amdgcn_s_barrier();            // buf[t&1] staged, visible to all
    const unsigned short* Ab = As + (t & 1)*4096;
    const unsigned short* Bb = Bs + (t & 1)*8192;
    short8 af[4], bf4[4];
    #pragma unroll
    for (int mt=0;mt<4;mt++) af[mt]  = *(const short8*)(Ab + (arow + mt*16)*32 + cOfs);
    #pragma unroll
    for (int nt=0;nt<4;nt++) bf4[nt] = *(const short8*)(Bb + (brow + nt*16)*32 + cOfs);
    __builtin_amdgcn_s_setprio(1);
    #pragma unroll
    for (int mt=0;mt<4;mt++)
      #pragma unroll
      for (int nt=0;nt<4;nt++)
        acc[mt][nt] = __builtin_amdgcn_mfma_f32_16x16x32_bf16(af[mt], bf4[nt], acc[mt][nt], 0,0,0);
    __builtin_amdgcn_s_setprio(0);
    __builtin_amdgcn_s_barrier();            // all waves' ds_reads of buf[t&1] retired
    if (t+2 < NT) STG(t+2);                  // overwrite buf[t&1]; lands under compute(t+1)
  }
#undef STG
  // ---- coalesced epilogue: per-wave 16x65-f32 LDS slab (overlays sm), out ----
  float* cb = (float*)sm + wave*1040;        // 8*1040*4 = 33.3 KB <= 48 KB
  const int rbase = q*4;
  const int gr0t = bm*128 + wr*64;
  const int gc0 = bn*256 + wc*64;
  #pragma unroll
  for (int mt=0; mt<4; mt++){
    #pragma unroll
    for (int nt=0;nt<4;nt++)
      #pragma unroll
      for (int r=0;r<4;r++)
        cb[(rbase+r)*65 + nt*16 + l15] = acc[mt][nt][r];
    int gr0 = gr0t + mt*16;
    if (epi == 0){
      float* po = (float*)((blockIdx.z < 2) ? outp : outp_hi)
                + (size_t)(blockIdx.z & 1) * ((size_t)M * N);
      int r4 = lane >> 4, c0f = (lane & 15)*4;
      #pragma unroll
      for (int h=0; h<4; h++){
        int row = h*4 + r4;
        float4 v;
        v.x = cb[row*65 + c0f + 0];
        v.y = cb[row*65 + c0f + 1];
        v.z = cb[row*65 + c0f + 2];
        v.w = cb[row*65 + c0f + 3];
        *(float4*)(po + (size_t)(gr0+row)*N + gc0 + c0f) = v;
      }
    } else {
      int r8 = lane >> 3, c0 = (lane & 7)*8;
      #pragma unroll
      for (int h=0; h<2; h++){
        int row = h*8 + r8;
        float v[8];
        #pragma unroll
        for (int u=0;u<8;u++) v[u] = cb[row*65 + c0 + u];
        if (epi == 1){
          #pragma unroll
          for (int u=0;u<8;u++) v[u] = gelu_f(v[u] + bias[gc0 + c0 + u]);
        }
        *(uint4*)((unsigned short*)outp + (size_t)(gr0+row)*N + gc0 + c0) = pack8(v);
      }
    }
  }
}

// ---------------- dt/dA per (token, head), written for both directions ----------------
__global__ __launch_bounds__(256) void dt_k(const unsigned short* __restrict__ zx,
    const float* __restrict__ dt_bias, const float* __restrict__ A_log,
    float* __restrict__ dAb, float* __restrict__ dtb){
  int b = blockIdx.y;
  int t = blockIdx.x*16 + (threadIdx.x>>4);
  int h = threadIdx.x & 15;
  float raw = b2f(zx[((size_t)b*LSEQ + t)*NPAD + (DINNER+CONVDIM) + h]) + dt_bias[h];
  float dt = (raw > 20.f) ? raw : log1pf(expf(raw));
  float dA = expf(-expf(A_log[h]) * dt);
  size_t f = ((size_t)b*LSEQ + t)*NHEADS + h;
  size_t r = ((size_t)(BSZ+b)*LSEQ + (LSEQ-1-t))*NHEADS + h;
  dAb[f] = dA; dtb[f] = dt;
  dAb[r] = dA; dtb[r] = dt;
}

// ---------------- conv+silu for x-channels, BOTH directions, + z compaction ----------
__global__ __launch_bounds__(256) void conv_x_k(const unsigned short* __restrict__ zx,
    const float* __restrict__ conv_w, const float* __restrict__ conv_b,
    const float* __restrict__ dtb, unsigned short* __restrict__ dtxb,
    unsigned short* __restrict__ zcomp){
  int b = blockIdx.y;
  int t0blk = blockIdx.x * 32;
  int tid = threadIdx.x;
  int half = tid >> 7, cg = tid & 127;
  int c0 = cg * 8;
  int head = c0 >> 6;
  float wk[4][8], bias8[8];
  #pragma unroll
  for (int k=0;k<4;k++)
    #pragma unroll
    for (int j=0;j<8;j++) wk[k][j] = conv_w[k*CONVDIM + c0 + j];
  #pragma unroll
  for (int j=0;j<8;j++) bias8[j] = conv_b[c0 + j];
  __shared__ float sdtf[32][16], sdtb[32][16];
  for (int r = tid; r < 512; r += 256){
    int i = r >> 4, h = r & 15;
    sdtf[i][h] = dtb[((size_t)b*LSEQ + t0blk + i)*NHEADS + h];
    sdtb[i][h] = dtb[((size_t)(BSZ+b)*LSEQ + (LSEQ-1-(t0blk+i)))*NHEADS + h];
  }
  __syncthreads();
  int t0 = t0blk + half*16;
  float w0[8],w1[8],w2[8],w3[8];
  #pragma unroll
  for (int j=0;j<8;j++){ w1[j]=0.f; w2[j]=0.f; w3[j]=0.f; }
  for (int it=0; it<22; ++it){
    int t = t0 - 3 + it;
    #pragma unroll
    for (int j=0;j<8;j++){ w0[j]=w1[j]; w1[j]=w2[j]; w2[j]=w3[j]; }
    if (t >= 0 && t < LSEQ){
      uint4 xv = *(const uint4*)(zx + ((size_t)b*LSEQ + t)*NPAD + DINNER + c0);
      const unsigned short* xs = (const unsigned short*)&xv;
      #pragma unroll
      for (int j=0;j<8;j++) w3[j] = b2f(xs[j]);
      if (t >= t0 && t < t0+16){
        uint4 zv = *(const uint4*)(zx + ((size_t)b*LSEQ + t)*NPAD + c0);
        *(uint4*)(zcomp + ((size_t)b*LSEQ + t)*DINNER + c0) = zv;
      }
    } else {
      #pragma unroll
      for (int j=0;j<8;j++) w3[j] = 0.f;
    }
    if (t >= t0 && t < t0+16){
      float dtf = sdtf[t - t0blk][head];
      float v[8];
      #pragma unroll
      for (int j=0;j<8;j++){
        float a = bias8[j] + wk[0][j]*w0[j] + wk[1][j]*w1[j] + wk[2][j]*w2[j] + wk[3][j]*w3[j];
        v[j] = (a / (1.f + __expf(-a))) * dtf;
      }
      *(uint4*)(dtxb + ((size_t)b*LSEQ + t)*DINNER + c0) = pack8(v);
    }
    int tau = t - 3;
    if (tau >= t0 && tau < t0+16){
      float dtv = sdtb[tau - t0blk][head];
      float v[8];
      #pragma unroll
      for (int j=0;j<8;j++){
        float a = bias8[j] + wk[0][j]*w3[j] + wk[1][j]*w2[j] + wk[2][j]*w1[j] + wk[3][j]*w0[j];
        v[j] = (a / (1.f + __expf(-a))) * dtv;
      }
      *(uint4*)(dtxb + ((size_t)(BSZ+b)*LSEQ + (LSEQ-1-tau))*DINNER + c0) = pack8(v);
    }
  }
}

// ---------------- conv+silu for B/C channels, both directions ----------------
__global__ __launch_bounds__(256) void conv_bc_k(const unsigned short* __restrict__ zx,
    const float* __restrict__ conv_w, const float* __restrict__ conv_b,
    unsigned short* __restrict__ Bb, unsigned short* __restrict__ Cb){
  int b = blockIdx.y;
  int t0blk = blockIdx.x * 64;
  int tid = threadIdx.x;
  int slot = tid >> 4, cg = tid & 15;
  int c0 = cg*8;
  int ccol = DINNER + 1024 + c0;
  int cw = 1024 + c0;
  float wk[4][8], bias8[8];
  #pragma unroll
  for (int k=0;k<4;k++)
    #pragma unroll
    for (int j=0;j<8;j++) wk[k][j] = conv_w[k*CONVDIM + cw + j];
  #pragma unroll
  for (int j=0;j<8;j++) bias8[j] = conv_b[cw + j];
  int t0 = t0blk + slot*4;
  float w0[8],w1[8],w2[8],w3[8];
  #pragma unroll
  for (int j=0;j<8;j++){ w1[j]=0.f; w2[j]=0.f; w3[j]=0.f; }
  for (int it=0; it<10; ++it){
    int t = t0 - 3 + it;
    #pragma unroll
    for (int j=0;j<8;j++){ w0[j]=w1[j]; w1[j]=w2[j]; w2[j]=w3[j]; }
    if (t >= 0 && t < LSEQ){
      uint4 xv = *(const uint4*)(zx + ((size_t)b*LSEQ + t)*NPAD + ccol);
      const unsigned short* xs = (const unsigned short*)&xv;
      #pragma unroll
      for (int j=0;j<8;j++) w3[j] = b2f(xs[j]);
    } else {
      #pragma unroll
      for (int j=0;j<8;j++) w3[j] = 0.f;
    }
    if (t >= t0 && t < t0+4){
      float v[8];
      #pragma unroll
      for (int j=0;j<8;j++){
        float a = bias8[j] + wk[0][j]*w0[j] + wk[1][j]*w1[j] + wk[2][j]*w2[j] + wk[3][j]*w3[j];
        v[j] = a / (1.f + __expf(-a));
      }
      size_t tok = (size_t)b*LSEQ + t;
      if (c0 < 64) *(uint4*)(Bb + tok*DSTATE + c0)      = pack8(v);
      else         *(uint4*)(Cb + tok*DSTATE + (c0-64)) = pack8(v);
    }
    int tau = t - 3;
    if (tau >= t0 && tau < t0+4){
      float v[8];
      #pragma unroll
      for (int j=0;j<8;j++){
        float a = bias8[j] + wk[0][j]*w3[j] + wk[1][j]*w2[j] + wk[2][j]*w1[j] + wk[3][j]*w0[j];
        v[j] = a / (1.f + __expf(-a));
      }
      size_t tok = (size_t)(BSZ+b)*LSEQ + (LSEQ-1-tau);
      if (c0 < 64) *(uint4*)(Bb + tok*DSTATE + c0)      = pack8(v);
      else         *(uint4*)(Cb + tok*DSTATE + (c0-64)) = pack8(v);
    }
  }
}

// ---- 64x64x64 bf16 GEMM on one wave, with optional chunk-XOR swizzle per operand.
// Swizzled layout: element (r, c) lives at r*72 + ((c>>3) ^ ((r>>3)&7))*8 + (c&7).
template<int SA, int SB>
__device__ inline void gemm64s(const unsigned short* Ab, const unsigned short* Bb_,
                               int l15, int q, f32x4 acc[4][4]){
  #pragma unroll
  for (int ks=0; ks<2; ks++){
    short8 af[4], bf4[4];
    #pragma unroll
    for (int mt=0;mt<4;mt++){
      int r = mt*16 + l15;
      int c = ks*4 + q; if (SA) c ^= (r>>3)&7;
      af[mt] = *(const short8*)(Ab + r*72 + c*8);
    }
    #pragma unroll
    for (int nt=0;nt<4;nt++){
      int r = nt*16 + l15;
      int c = ks*4 + q; if (SB) c ^= (r>>3)&7;
      bf4[nt] = *(const short8*)(Bb_ + r*72 + c*8);
    }
    #pragma unroll
    for (int mt=0;mt<4;mt++)
      #pragma unroll
      for (int nt=0;nt<4;nt++)
        acc[mt][nt] = __builtin_amdgcn_mfma_f32_16x16x32_bf16(af[mt], bf4[nt], acc[mt][nt], 0,0,0);
  }
}
__device__ inline void gemm64(const unsigned short* Ab, const unsigned short* Bb_,
                              int l15, int q, f32x4 acc[4][4]){
  gemm64s<0,0>(Ab, Bb_, l15, q, acc);
}

// ---------------- SSD pass 1: per chunk: Y_intra (masked attention form) + local state G ----
// Transpose-fills (S3 dtx, S2 decay-B) and the masked-P fill use the chunk-XOR
// swizzle (16-way / 4-way bank conflicts otherwise); matching gemm64s reads.
__global__ __launch_bounds__(64) void ssd1_k(const float* __restrict__ dAb,
    const unsigned short* __restrict__ dtxb, const unsigned short* __restrict__ Bb,
    const unsigned short* __restrict__ Cb,
    unsigned short* __restrict__ y0, unsigned short* __restrict__ y1,
    unsigned short* __restrict__ hbuf, float* __restrict__ Pch, float* __restrict__ ebuf){
  int ch = blockIdx.x, h = blockIdx.y, z = blockIdx.z;
  int d = z >> 1, b = z & 1;
  int lane = threadIdx.x;
  int l15 = lane & 15, q = lane >> 4;
  int tr = lane >> 3, cb8 = (lane & 7)*8;
  int m7 = lane & 7;                       // = (cb8+j)>>3 for j in [0,8)
  size_t tokb = (size_t)z*LSEQ + (size_t)ch*64;
  size_t zhc = ((size_t)z*NHEADS + h)*NCH + ch;
  __shared__ __align__(16) unsigned short S1[64*72];
  __shared__ __align__(16) unsigned short S2[64*72];
  __shared__ __align__(16) unsigned short S3[64*72];
  __shared__ float Lb[64];
  float L = fmaxf(logf(dAb[(tokb + lane)*NHEADS + h]), -60.f);
  #pragma unroll
  for (int off=1; off<64; off<<=1){
    float v = __shfl_up(L, off);
    if (lane >= off) L += v;
  }
  Lb[lane] = L;
  float e = __expf(L);
  ebuf[zhc*64 + lane] = e;
  if (lane == 63) Pch[zhc] = e;
  for (int i=0;i<8;i++){
    int t = i*8 + tr;
    *(uint4*)&S1[t*72 + cb8] = *(const uint4*)(Cb + (tokb+t)*DSTATE + cb8);
    *(uint4*)&S2[t*72 + cb8] = *(const uint4*)(Bb + (tokb+t)*DSTATE + cb8);
    uint4 xv = *(const uint4*)(dtxb + (tokb+t)*DINNER + (size_t)h*64 + cb8);
    const unsigned short* xs = (const unsigned short*)&xv;
    int csw = ((i ^ m7) << 3) + tr;        // swizzled column for token t
    #pragma unroll
    for (int j=0;j<8;j++) S3[(cb8+j)*72 + csw] = xs[j];
  }
  f32x4 sa[4][4];
  for (int i=0;i<4;i++) for (int j=0;j<4;j++) sa[i][j] = (f32x4){0.f,0.f,0.f,0.f};
  gemm64s<0,0>(S1, S2, l15, q, sa);
  float Lsv[4];
  #pragma unroll
  for (int nt=0;nt<4;nt++) Lsv[nt] = Lb[nt*16 + l15];
  int sch = l15 >> 3, sin = l15 & 7;       // s-chunk parity / within-chunk
  #pragma unroll
  for (int mt=0;mt<4;mt++){
    #pragma unroll
    for (int r=0;r<4;r++){
      int t = mt*16 + q*4 + r;
      int trow = (t>>3)&7;
      float Lt = Lb[t];
      #pragma unroll
      for (int nt=0;nt<4;nt++){
        int s = nt*16 + l15;
        float v = (t >= s) ? __expf(Lt - Lsv[nt]) * sa[mt][nt][r] : 0.f;
        S1[t*72 + (((nt*2 + sch) ^ trow)<<3) + sin] = f2b(v);   // swizzled P
      }
    }
  }
  f32x4 ya[4][4];
  for (int i=0;i<4;i++) for (int j=0;j<4;j++) ya[i][j] = (f32x4){0.f,0.f,0.f,0.f};
  gemm64s<1,1>(S1, S3, l15, q, ya);
  #pragma unroll
  for (int mt=0;mt<4;mt++)
    #pragma unroll
    for (int pt=0;pt<4;pt++)
      #pragma unroll
      for (int r=0;r<4;r++)
        S2[(mt*16+q*4+r)*72 + pt*16 + l15] = f2b(ya[mt][pt][r]);
  unsigned short* yb = d ? y1 : y0;
  for (int i=0;i<8;i++){
    int t = i*8 + tr; int g = ch*64 + t;
    int tph = d ? (LSEQ-1-g) : g;
    *(uint4*)(yb + ((size_t)b*LSEQ + tph)*DINNER + (size_t)h*64 + cb8) = *(uint4*)&S2[t*72 + cb8];
  }
  float L63 = Lb[63];
  for (int i=0;i<8;i++){
    int s = i*8 + tr;
    float w = __expf(L63 - Lb[s]);
    uint4 bv = *(const uint4*)(Bb + (tokb+s)*DSTATE + cb8);
    const unsigned short* bs = (const unsigned short*)&bv;
    int csw = ((i ^ m7) << 3) + tr;        // swizzled column for token s
    #pragma unroll
    for (int j=0;j<8;j++) S2[(cb8+j)*72 + csw] = f2b(w * b2f(bs[j]));
  }
  f32x4 ga[4][4];
  for (int i=0;i<4;i++) for (int j=0;j<4;j++) ga[i][j] = (f32x4){0.f,0.f,0.f,0.f};
  gemm64s<1,1>(S3, S2, l15, q, ga);
  #pragma unroll
  for (int pt=0;pt<4;pt++)
    #pragma unroll
    for (int nt=0;nt<4;nt++)
      #pragma unroll
      for (int r=0;r<4;r++)
        S1[(pt*16+q*4+r)*72 + nt*16 + l15] = f2b(ga[pt][nt][r]);
  for (int i=0;i<8;i++){
    int p = i*8 + tr;
    *(uint4*)(hbuf + zhc*4096 + (size_t)p*64 + cb8) = *(uint4*)&S1[p*72 + cb8];
  }
}

// ---------------- combine chunk states, IN PLACE (4-way over state dim, prefetched) ----
__global__ __launch_bounds__(256) void comb_k(unsigned short* __restrict__ hbuf,
    const float* __restrict__ Pch){
  int u = blockIdx.x; int tid = threadIdx.x;
  int kb = blockIdx.y * 4;
  size_t base0 = ((size_t)u*NCH)*4096;
  float hreg[4];
  unsigned short ccur[4], cnxt[4] = {0,0,0,0};
  #pragma unroll
  for (int k=0;k<4;k++){ hreg[k]=0.f; ccur[k] = hbuf[base0 + tid + (size_t)(kb+k)*256]; }
  float Pc = Pch[(size_t)u*NCH], Pn = 0.f;
  for (int ch=0; ch<NCH; ch++){
    size_t base = base0 + (size_t)ch*4096;
    if (ch+1 < NCH){
      size_t bnx = base + 4096;
      #pragma unroll
      for (int k=0;k<4;k++) cnxt[k] = hbuf[bnx + tid + (size_t)(kb+k)*256];
      Pn = Pch[(size_t)u*NCH + ch + 1];
    }
    #pragma unroll
    for (int k=0;k<4;k++){
      hbuf[base + tid + (size_t)(kb+k)*256] = f2b(hreg[k]);
      hreg[k] = hreg[k]*Pc + b2f(ccur[k]);
    }
    #pragma unroll
    for (int k=0;k<4;k++) ccur[k] = cnxt[k];
    Pc = Pn;
  }
}

// ---------------- SSD pass 2: Y += diag(e) C h_in^T + D*xh ----------------
__global__ __launch_bounds__(64) void ssd2_k(const unsigned short* __restrict__ Cb,
    const unsigned short* __restrict__ hbuf, const unsigned short* __restrict__ dtxb,
    const float* __restrict__ dtb, const float* __restrict__ ebuf, const float* __restrict__ Dh,
    unsigned short* __restrict__ y0, unsigned short* __restrict__ y1){
  int ch = blockIdx.x, h = blockIdx.y, z = blockIdx.z;
  int d = z >> 1, b = z & 1;
  int lane = threadIdx.x;
  int l15 = lane & 15, q = lane >> 4;
  int tr = lane >> 3, cb8 = (lane & 7)*8;
  size_t tokb = (size_t)z*LSEQ + (size_t)ch*64;
  size_t zhc = ((size_t)z*NHEADS + h)*NCH + ch;
  __shared__ __align__(16) unsigned short S1[64*72];
  __shared__ __align__(16) unsigned short S2[64*72];
  __shared__ __align__(16) unsigned short S3[64*72];
  __shared__ float eb2[64], dti[64];
  eb2[lane] = ebuf[zhc*64 + lane];
  dti[lane] = 1.f / dtb[(tokb + lane)*NHEADS + h];
  float Dv = Dh[h];
  for (int i=0;i<8;i++){
    int t = i*8 + tr;
    *(uint4*)&S1[t*72 + cb8] = *(const uint4*)(Cb + (tokb+t)*DSTATE + cb8);
    *(uint4*)&S2[t*72 + cb8] = *(const uint4*)(hbuf + zhc*4096 + (size_t)t*64 + cb8);
  }
  f32x4 acc[4][4];
  for (int i=0;i<4;i++) for (int j=0;j<4;j++) acc[i][j] = (f32x4){0.f,0.f,0.f,0.f};
  gemm64(S1, S2, l15, q, acc);
  unsigned short* yb = d ? y1 : y0;
  #pragma unroll
  for (int mt=0;mt<4;mt++){
    #pragma unroll
    for (int r=0;r<4;r++){
      int t = mt*16 + q*4 + r; int g = ch*64 + t;
      int tph = d ? (LSEQ-1-g) : g;
      size_t rowb = ((size_t)b*LSEQ + tph)*DINNER + (size_t)h*64;
      size_t dxb_ = (tokb + t)*DINNER + (size_t)h*64;
      float et = eb2[t], di = dti[t];
      #pragma unroll
      for (int pt=0;pt<4;pt++){
        int p = pt*16 + l15;
        float v = acc[mt][pt][r]*et + b2f(yb[rowb + p]) + Dv * b2f(dtxb[dxb_ + p]) * di;
        S3[t*72 + p] = f2b(v);
      }
    }
  }
  for (int i=0;i<8;i++){
    int t = i*8 + tr; int g = ch*64 + t;
    int tph = d ? (LSEQ-1-g) : g;
    *(uint4*)(yb + ((size_t)b*LSEQ + tph)*DINNER + (size_t)h*64 + cb8) = *(uint4*)&S3[t*72 + cb8];
  }
}

// ---------------- gate: g=y*silu(z), per-dir rmsnorm, sum, ->bf16 ----------------
__global__ __launch_bounds__(256) void gate_k(const unsigned short* __restrict__ y0,
    const unsigned short* __restrict__ y1, const unsigned short* __restrict__ zcomp,
    const float* __restrict__ mnw, unsigned short* __restrict__ gsum){
  int tok = blockIdx.x; int tid = threadIdx.x;
  __shared__ float g0s[DINNER], g1s[DINNER];
  float ss0 = 0.f, ss1 = 0.f;
  for (int i=0;i<4;i++){
    int c = tid + i*256;
    float z = b2f(zcomp[(size_t)tok*DINNER + c]);
    float sz = z / (1.f + __expf(-z));
    float g0 = b2f(y0[(size_t)tok*DINNER + c]) * sz;
    float g1 = b2f(y1[(size_t)tok*DINNER + c]) * sz;
    g0s[c] = g0; g1s[c] = g1;
    ss0 += g0*g0; ss1 += g1*g1;
  }
  for (int m=32;m>=1;m>>=1){ ss0 += __shfl_xor(ss0,m); ss1 += __shfl_xor(ss1,m); }
  __shared__ float w0[4], w1[4];
  int wave = tid>>6, lane = tid&63;
  if (lane==0){ w0[wave]=ss0; w1[wave]=ss1; }
  __syncthreads();
  ss0 = w0[0]+w0[1]+w0[2]+w0[3];
  ss1 = w1[0]+w1[1]+w1[2]+w1[3];
  float r0 = rsqrtf(ss0*(1.f/DINNER) + 1e-5f);
  float r1 = rsqrtf(ss1*(1.f/DINNER) + 1e-5f);
  for (int i=0;i<4;i++){
    int c = tid + i*256;
    gsum[(size_t)tok*DINNER + c] = f2b((g0s[c]*r0 + g1s[c]*r1) * mnw[c]);
  }
}

extern "C" void kernel_launch(void* const* d_in, const int* in_sizes, int n_in,
                              void* d_out, int out_size, void* d_ws, size_t ws_size,
                              hipStream_t stream){
  const float* x       = (const float*)d_in[0];
  const float* nin_w   = (const float*)d_in[1];
  const float* nin_b   = (const float*)d_in[2];
  const float* nout_w  = (const float*)d_in[3];
  const float* nout_b  = (const float*)d_in[4];
  const float* in_w    = (const float*)d_in[5];
  const float* conv_w  = (const float*)d_in[6];
  const float* conv_b  = (const float*)d_in[7];
  const float* dt_bias = (const float*)d_in[8];
  const float* A_log   = (const float*)d_in[9];
  const float* D_h     = (const float*)d_in[10];
  const float* mnorm_w = (const float*)d_in[11];
  const float* out_w   = (const float*)d_in[12];
  const float* ff_w1   = (const float*)d_in[13];
  const float* ff_b1   = (const float*)d_in[14];
  const float* ff_w2   = (const float*)d_in[15];
  const float* ff_b2   = (const float*)d_in[16];
  float* out = (float*)d_out;

  char* ws = (char*)d_ws;
  size_t off = 0;
  auto alloc = [&](size_t bytes)->char*{
    char* p = ws + off; off = (off + bytes + 255) & ~(size_t)255; return p; };
  unsigned short* xn_bf = (unsigned short*)alloc((size_t)NTOK*DMODEL*2);    // 8.4 MB
  unsigned short* in_wT = (unsigned short*)alloc((size_t)NPAD*DMODEL*2);
  unsigned short* out_wT= (unsigned short*)alloc((size_t)DMODEL*DINNER*2);
  unsigned short* w1T   = (unsigned short*)alloc((size_t)2048*DMODEL*2);
  unsigned short* w2T   = (unsigned short*)alloc((size_t)DMODEL*2048*2);
  unsigned short* zx    = (unsigned short*)alloc((size_t)NTOK*NPAD*2);      // 37.7 MB
  unsigned short* zcomp = (unsigned short*)alloc((size_t)NTOK*DINNER*2);    // 16.8 MB
  float*          dAb   = (float*)alloc((size_t)2*NTOK*NHEADS*4);
  float*          dtb   = (float*)alloc((size_t)2*NTOK*NHEADS*4);
  unsigned short* Bb    = (unsigned short*)alloc((size_t)2*NTOK*DSTATE*2);
  unsigned short* Cb    = (unsigned short*)alloc((size_t)2*NTOK*DSTATE*2);
  unsigned short* dtxb  = (unsigned short*)alloc((size_t)2*NTOK*DINNER*2);  // 33.6 MB
  unsigned short* y0    = (unsigned short*)alloc((size_t)NTOK*DINNER*2);    // 16.8 MB
  unsigned short* y1    = (unsigned short*)alloc((size_t)NTOK*DINNER*2);    // 16.8 MB (contiguous after y0)
  float*          Pch   = (float*)alloc((size_t)64*NCH*4);
  float*          ebuf  = (float*)alloc((size_t)64*NCH*64*4);               // 1.05 MB
  size_t need = off;
  if (need > ws_size) return;  // fail absmax cleanly instead of faulting

  // aliases into sequentially-dead regions (stream order makes each safe):
  unsigned short* hbuf  = zx;        // chunk states; zx dead after conv kernels
  unsigned short* gsum  = dtxb;      // dtxb dead after ssd2_k
  float* mp01 = (float*)zx;          // out_proj partials z=0,1 (hbuf dead after ssd2)
  float* mp23 = (float*)y0;          // out_proj partials z=2,3 (y0+y1 dead after gate)
  unsigned short* m_bf  = xn_bf;     // LN4 out (xn_bf dead after in_proj)
  unsigned short* h1    = zx;        // ff1 out (mp01 dead after LN4)
  float* fp01 = (float*)dtxb;        // ff2 partials z=0,1 (gsum dead after out_proj)
  float* fp23 = (float*)y0;          // ff2 partials z=2,3 (mp23 dead after LN4)

  // weight transposes -> bf16 [N][K]
  wconv_t<<<dim3(NPAD/32,   DMODEL/32), 256, 0, stream>>>(in_w,  in_wT,  DMODEL, DPROJ,  NPAD);
  wconv_t<<<dim3(DMODEL/32, DINNER/32), 256, 0, stream>>>(out_w, out_wT, DINNER, DMODEL, DMODEL);
  wconv_t<<<dim3(2048/32,   DMODEL/32), 256, 0, stream>>>(ff_w1, w1T,    DMODEL, 2048,   2048);
  wconv_t<<<dim3(DMODEL/32, 2048/32),   256, 0, stream>>>(ff_w2, w2T,    2048,   DMODEL, DMODEL);
  // LN in -> bf16
  layernorm_k<<<NTOK, 256, 0, stream>>>(x, nin_w, nin_b, xn_bf);
  // in_proj -> bf16 zx   [128x256, 2 blocks/CU]
  gemm128_k<<<dim3(NPAD/256, NTOK/128, 1), 512, 0, stream>>>(xn_bf, in_wT, zx, nullptr, NTOK, NPAD, DMODEL, DMODEL, 3, nullptr);
  // dt/dA then conv (both directions from one pass) + z compaction
  dt_k<<<dim3(LSEQ/16, BSZ), 256, 0, stream>>>(zx, dt_bias, A_log, dAb, dtb);
  conv_x_k<<<dim3(LSEQ/32, BSZ), 256, 0, stream>>>(zx, conv_w, conv_b, dtb, dtxb, zcomp);
  conv_bc_k<<<dim3(LSEQ/64, BSZ), 256, 0, stream>>>(zx, conv_w, conv_b, Bb, Cb);
  // chunked SSD: intra-chunk (MFMA) -> combine -> inter-chunk (MFMA)
  ssd1_k<<<dim3(NCH, NHEADS, 2*BSZ), 64, 0, stream>>>(dAb, dtxb, Bb, Cb, y0, y1, hbuf, Pch, ebuf);
  comb_k<<<dim3(64, 4), 256, 0, stream>>>(hbuf, Pch);
  ssd2_k<<<dim3(NCH, NHEADS, 2*BSZ), 64, 0, stream>>>(Cb, hbuf, dtxb, dtb, ebuf, D_h, y0, y1);
  // gate + per-dir rmsnorm + sum (linearity: single out_proj GEMM)
  gate_k<<<NTOK, 256, 0, stream>>>(y0, y1, zcomp, mnorm_w, gsum);
  // out_proj: split-K=4 -> f32 partials mp01[2], mp23[2]
  gemm128_k<<<dim3(DMODEL/256, NTOK/128, 4), 512, 0, stream>>>(gsum, out_wT, mp01, mp23, NTOK, DMODEL, DINNER, 256, 0, nullptr);
  // LN out over sum of 4 partials -> bf16 (m_bf = xn_bf region)
  layernorm4_k<<<NTOK, 256, 0, stream>>>(mp01, mp01 + (size_t)NTOK*DMODEL, mp23, mp23 + (size_t)NTOK*DMODEL, nout_w, nout_b, m_bf);
  // ff1 + gelu -> bf16
  gemm128_k<<<dim3(2048/256, NTOK/128, 1), 512, 0, stream>>>(m_bf, w1T, h1, nullptr, NTOK, 2048, DMODEL, DMODEL, 1, ff_b1);
  // ff2: split-K=4 -> f32 partials fp01[2], fp23[2]
  gemm128_k<<<dim3(DMODEL/256, NTOK/128, 4), 512, 0, stream>>>(h1, w2T, fp01, fp23, NTOK, DMODEL, 2048, 512, 0, nullptr);
  // reduce partials + bias + residual -> f32 out
  reduce4_k<<<2048, 256, 0, stream>>>(fp01, fp23, ff_b2, x, out);
}

// Round 7
// 366.088 us; speedup vs baseline: 1.1028x; 1.0891x over previous
//
#include <hip/hip_runtime.h>
#include <hip/hip_bf16.h>

#define LSEQ 4096
#define BSZ 2
#define DMODEL 512
#define DINNER 1024
#define DSTATE 64
#define NHEADS 16
#define CONVDIM 1152
#define DPROJ 2192
#define NPAD 2304
#define NTOK (BSZ*LSEQ)
#define NCH 64   /* 64-token chunks */

typedef __attribute__((ext_vector_type(8))) short short8;
typedef __attribute__((ext_vector_type(4))) float f32x4;

__device__ inline unsigned short f2b(float v){
  unsigned int u = __builtin_bit_cast(unsigned int, v);
  unsigned int r = (u + 0x7FFFu + ((u >> 16) & 1u)) >> 16;
  return (unsigned short)r;
}
__device__ inline float b2f(unsigned short u){
  unsigned int x = ((unsigned int)u) << 16;
  return __builtin_bit_cast(float, x);
}
__device__ inline uint4 pack8(const float* v){
  uint4 pk;
  pk.x = (unsigned)f2b(v[0]) | ((unsigned)f2b(v[1])<<16);
  pk.y = (unsigned)f2b(v[2]) | ((unsigned)f2b(v[3])<<16);
  pk.z = (unsigned)f2b(v[4]) | ((unsigned)f2b(v[5])<<16);
  pk.w = (unsigned)f2b(v[6]) | ((unsigned)f2b(v[7])<<16);
  return pk;
}
// tanh-form gelu (max abs err ~3e-4 vs exact erf form; far below bf16 noise here)
__device__ inline float gelu_f(float x){
  float x2 = x*x;
  float u = x*(0.7978845608f + 0.0356774081f*x2);
  float au = fabsf(u);
  float z = __expf(-2.f*au);
  float t = (1.f - z)/(1.f + z);
  t = (u >= 0.f) ? t : -t;
  return 0.5f*x*(1.f + t);
}

#define GLL16(gp, lp) __builtin_amdgcn_global_load_lds( \
    (const __attribute__((address_space(1))) unsigned int*)(gp), \
    (__attribute__((address_space(3))) unsigned int*)(lp), 16, 0, 0)

// ---------------- weight transpose + f32->bf16 (src [K][Nsrc] -> dst [Npad][K]) ----
__global__ __launch_bounds__(256) void wconv_t(const float* __restrict__ src,
    unsigned short* __restrict__ dst, int K, int Nsrc, int Npad){
  __shared__ float t[32][33];
  int n0 = blockIdx.x*32, k0 = blockIdx.y*32;
  int tx = threadIdx.x & 31, ty = threadIdx.x >> 5;
  for (int i=0;i<4;i++){
    int k = k0 + ty + i*8; int n = n0 + tx;
    t[ty + i*8][tx] = (n < Nsrc) ? src[(size_t)k*Nsrc + n] : 0.f;
  }
  __syncthreads();
  for (int i=0;i<4;i++){
    int n = n0 + ty + i*8; int k = k0 + tx;
    if (n < Npad) dst[(size_t)n*K + k] = f2b(t[tx][ty + i*8]);
  }
}

// ---------------- layernorm over 512 cols (f32 in) -> bf16 ----------------
__global__ __launch_bounds__(256) void layernorm_k(const float* __restrict__ in,
    const float* __restrict__ w, const float* __restrict__ bb, unsigned short* __restrict__ out){
  int row = blockIdx.x; int tid = threadIdx.x;
  const float* r = in + (size_t)row*DMODEL;
  float v0 = r[tid], v1 = r[tid+256];
  float s = v0+v1, sq = v0*v0+v1*v1;
  for (int m=32;m>=1;m>>=1){ s += __shfl_xor(s,m); sq += __shfl_xor(sq,m); }
  __shared__ float ws_[4], wq_[4];
  int wave = tid>>6, lane = tid&63;
  if (lane==0){ ws_[wave]=s; wq_[wave]=sq; }
  __syncthreads();
  s = ws_[0]+ws_[1]+ws_[2]+ws_[3]; sq = wq_[0]+wq_[1]+wq_[2]+wq_[3];
  float mu = s * (1.f/DMODEL);
  float var = sq * (1.f/DMODEL) - mu*mu;
  float rs = rsqrtf(var + 1e-5f);
  out[(size_t)row*DMODEL + tid]     = f2b((v0-mu)*rs*w[tid] + bb[tid]);
  out[(size_t)row*DMODEL + tid+256] = f2b((v1-mu)*rs*w[tid+256] + bb[tid+256]);
}

// ---------------- layernorm over 512 cols of (p0+p1+p2+p3) (split-K partials) -> bf16 ----
__global__ __launch_bounds__(256) void layernorm4_k(const float* __restrict__ in0,
    const float* __restrict__ in1, const float* __restrict__ in2, const float* __restrict__ in3,
    const float* __restrict__ w, const float* __restrict__ bb, unsigned short* __restrict__ out){
  int row = blockIdx.x; int tid = threadIdx.x;
  size_t o = (size_t)row*DMODEL;
  float v0 = in0[o+tid] + in1[o+tid] + in2[o+tid] + in3[o+tid];
  float v1 = in0[o+tid+256] + in1[o+tid+256] + in2[o+tid+256] + in3[o+tid+256];
  float s = v0+v1, sq = v0*v0+v1*v1;
  for (int m=32;m>=1;m>>=1){ s += __shfl_xor(s,m); sq += __shfl_xor(sq,m); }
  __shared__ float ws_[4], wq_[4];
  int wave = tid>>6, lane = tid&63;
  if (lane==0){ ws_[wave]=s; wq_[wave]=sq; }
  __syncthreads();
  s = ws_[0]+ws_[1]+ws_[2]+ws_[3]; sq = wq_[0]+wq_[1]+wq_[2]+wq_[3];
  float mu = s * (1.f/DMODEL);
  float var = sq * (1.f/DMODEL) - mu*mu;
  float rs = rsqrtf(var + 1e-5f);
  out[o + tid]     = f2b((v0-mu)*rs*w[tid] + bb[tid]);
  out[o + tid+256] = f2b((v1-mu)*rs*w[tid+256] + bb[tid+256]);
}

// ---------------- ff2 split-K reduce: out = p0+p1+p2+p3 + bias + resid (f32) -------
__global__ __launch_bounds__(256) void reduce4_k(const float* __restrict__ pa,
    const float* __restrict__ pb, const float* __restrict__ bias,
    const float* __restrict__ resid, float* __restrict__ out){
  const size_t MN4 = (size_t)NTOK*DMODEL/4;
  for (size_t i = (size_t)blockIdx.x*256 + threadIdx.x; i < MN4; i += (size_t)gridDim.x*256){
    float4 a0 = ((const float4*)pa)[i];
    float4 a1 = ((const float4*)pa)[i + MN4];
    float4 b0 = ((const float4*)pb)[i];
    float4 b1 = ((const float4*)pb)[i + MN4];
    float4 rv = ((const float4*)resid)[i];
    int col = (int)((i*4) & (DMODEL-1));
    const float4 bs = *(const float4*)(bias + col);
    float4 o;
    o.x = a0.x + a1.x + b0.x + b1.x + bs.x + rv.x;
    o.y = a0.y + a1.y + b0.y + b1.y + bs.y + rv.y;
    o.z = a0.z + a1.z + b0.z + b1.z + bs.z + rv.z;
    o.w = a0.w + a1.w + b0.w + b1.w + bs.w + rv.w;
    ((float4*)out)[i] = o;
  }
}

// ---------------- 128x256-tile bf16 GEMM, BK=32 dbuf, 2 blocks/CU (TLP regime) ------
__global__ __launch_bounds__(512, 4) void gemm128_k(const unsigned short* __restrict__ A,
    const unsigned short* __restrict__ Bt, void* __restrict__ outp, void* __restrict__ outp_hi,
    int M, int N, int K, int klen, int epi, const float* __restrict__ bias){
  __shared__ __align__(16) unsigned short sm[24576];   // 48 KiB
  unsigned short* As = sm;           // [2][128][32]
  unsigned short* Bs = sm + 8192;    // [2][256][32]
  const int tid = threadIdx.x;
  const int lane = tid & 63, wave = tid >> 6;
  const int wr = wave >> 2, wc = wave & 3;   // 2 M-groups x 4 N-groups, 64x64/wave
  const int l15 = lane & 15, q = lane >> 4;
  int nbx = gridDim.x;
  int bid = blockIdx.y * nbx + blockIdx.x;
  int cpx = (nbx * gridDim.y) >> 3;
  int swz = (bid & 7) * cpx + (bid >> 3);
  int bn = swz % nbx, bm = swz / nbx;
  const int kstart = blockIdx.z * klen;
  const int NT = klen >> 5;                  // BK = 32
  const int ra  = tid >> 2;
  const int sca = (tid & 3) ^ ((ra >> 1) & 3);
  const int jb1 = tid + 512;
  const int rb1 = jb1 >> 2;
  const int scb1 = (jb1 & 3) ^ ((rb1 >> 1) & 3);
  const unsigned short* ga  = A  + (size_t)(bm*128 + ra )*K + kstart + sca*8;
  const unsigned short* gb0 = Bt + (size_t)(bn*256 + ra )*K + kstart + sca*8;
  const unsigned short* gb1 = Bt + (size_t)(bn*256 + rb1)*K + kstart + scb1*8;
  unsigned short* lAa = As + tid*8;
  unsigned short* lB0 = Bs + tid*8;
  unsigned short* lB1 = Bs + jb1*8;
#define STG(t) { const int go=(t)*32, loa=((t)&1)*4096, lob=((t)&1)*8192; \
  GLL16(ga+go, lAa+loa); GLL16(gb0+go, lB0+lob); GLL16(gb1+go, lB1+lob); }
  f32x4 acc[4][4];
  #pragma unroll
  for (int i=0;i<4;i++)
    #pragma unroll
    for (int j=0;j<4;j++) acc[i][j] = (f32x4){0.f,0.f,0.f,0.f};
  STG(0); STG(1);                            // 6 loads/thread in flight
  const int cOfs = (q ^ ((l15 >> 1) & 3)) * 8;
  const int arow = wr*64 + l15;
  const int brow = wc*64 + l15;
  for (int t = 0; t < NT; ++t){
    if (t+1 < NT) { asm volatile("s_waitcnt vmcnt(3)" ::: "memory"); }
    else          { asm volatile("s_waitcnt vmcnt(0)" ::: "memory"); }
    __builtin_amdgcn_s_barrier();            // buf[t&1] staged, visible to all
    const unsigned short* Ab = As + (t & 1)*4096;
    const unsigned short* Bb = Bs + (t & 1)*8192;
    short8 af[4], bf4[4];
    #pragma unroll
    for (int mt=0;mt<4;mt++) af[mt]  = *(const short8*)(Ab + (arow + mt*16)*32 + cOfs);
    #pragma unroll
    for (int nt=0;nt<4;nt++) bf4[nt] = *(const short8*)(Bb + (brow + nt*16)*32 + cOfs);
    __builtin_amdgcn_s_setprio(1);
    #pragma unroll
    for (int mt=0;mt<4;mt++)
      #pragma unroll
      for (int nt=0;nt<4;nt++)
        acc[mt][nt] = __builtin_amdgcn_mfma_f32_16x16x32_bf16(af[mt], bf4[nt], acc[mt][nt], 0,0,0);
    __builtin_amdgcn_s_setprio(0);
    __builtin_amdgcn_s_barrier();            // all waves' ds_reads of buf[t&1] retired
    if (t+2 < NT) STG(t+2);                  // overwrite buf[t&1]; lands under compute(t+1)
  }
#undef STG
  // ---- coalesced epilogue: per-wave 16x65-f32 LDS slab (overlays sm), out ----
  float* cb = (float*)sm + wave*1040;        // 8*1040*4 = 33.3 KB <= 48 KB
  const int rbase = q*4;
  const int gr0t = bm*128 + wr*64;
  const int gc0 = bn*256 + wc*64;
  #pragma unroll
  for (int mt=0; mt<4; mt++){
    #pragma unroll
    for (int nt=0;nt<4;nt++)
      #pragma unroll
      for (int r=0;r<4;r++)
        cb[(rbase+r)*65 + nt*16 + l15] = acc[mt][nt][r];
    int gr0 = gr0t + mt*16;
    if (epi == 0){
      float* po = (float*)((blockIdx.z < 2) ? outp : outp_hi)
                + (size_t)(blockIdx.z & 1) * ((size_t)M * N);
      int r4 = lane >> 4, c0f = (lane & 15)*4;
      #pragma unroll
      for (int h=0; h<4; h++){
        int row = h*4 + r4;
        float4 v;
        v.x = cb[row*65 + c0f + 0];
        v.y = cb[row*65 + c0f + 1];
        v.z = cb[row*65 + c0f + 2];
        v.w = cb[row*65 + c0f + 3];
        *(float4*)(po + (size_t)(gr0+row)*N + gc0 + c0f) = v;
      }
    } else {
      int r8 = lane >> 3, c0 = (lane & 7)*8;
      #pragma unroll
      for (int h=0; h<2; h++){
        int row = h*8 + r8;
        float v[8];
        #pragma unroll
        for (int u=0;u<8;u++) v[u] = cb[row*65 + c0 + u];
        if (epi == 1){
          #pragma unroll
          for (int u=0;u<8;u++) v[u] = gelu_f(v[u] + bias[gc0 + c0 + u]);
        }
        *(uint4*)((unsigned short*)outp + (size_t)(gr0+row)*N + gc0 + c0) = pack8(v);
      }
    }
  }
}

// ---------------- dt/dA per (token, head), written for both directions ----------------
__global__ __launch_bounds__(256) void dt_k(const unsigned short* __restrict__ zx,
    const float* __restrict__ dt_bias, const float* __restrict__ A_log,
    float* __restrict__ dAb, float* __restrict__ dtb){
  int b = blockIdx.y;
  int t = blockIdx.x*16 + (threadIdx.x>>4);
  int h = threadIdx.x & 15;
  float raw = b2f(zx[((size_t)b*LSEQ + t)*NPAD + (DINNER+CONVDIM) + h]) + dt_bias[h];
  float dt = (raw > 20.f) ? raw : log1pf(expf(raw));
  float dA = expf(-expf(A_log[h]) * dt);
  size_t f = ((size_t)b*LSEQ + t)*NHEADS + h;
  size_t r = ((size_t)(BSZ+b)*LSEQ + (LSEQ-1-t))*NHEADS + h;
  dAb[f] = dA; dtb[f] = dt;
  dAb[r] = dA; dtb[r] = dt;
}

// ---------------- conv+silu for x-channels, BOTH directions, + z compaction ----------
__global__ __launch_bounds__(256) void conv_x_k(const unsigned short* __restrict__ zx,
    const float* __restrict__ conv_w, const float* __restrict__ conv_b,
    const float* __restrict__ dtb, unsigned short* __restrict__ dtxb,
    unsigned short* __restrict__ zcomp){
  int b = blockIdx.y;
  int t0blk = blockIdx.x * 32;
  int tid = threadIdx.x;
  int half = tid >> 7, cg = tid & 127;
  int c0 = cg * 8;
  int head = c0 >> 6;
  float wk[4][8], bias8[8];
  #pragma unroll
  for (int k=0;k<4;k++)
    #pragma unroll
    for (int j=0;j<8;j++) wk[k][j] = conv_w[k*CONVDIM + c0 + j];
  #pragma unroll
  for (int j=0;j<8;j++) bias8[j] = conv_b[c0 + j];
  __shared__ float sdtf[32][16], sdtb[32][16];
  for (int r = tid; r < 512; r += 256){
    int i = r >> 4, h = r & 15;
    sdtf[i][h] = dtb[((size_t)b*LSEQ + t0blk + i)*NHEADS + h];
    sdtb[i][h] = dtb[((size_t)(BSZ+b)*LSEQ + (LSEQ-1-(t0blk+i)))*NHEADS + h];
  }
  __syncthreads();
  int t0 = t0blk + half*16;
  float w0[8],w1[8],w2[8],w3[8];
  #pragma unroll
  for (int j=0;j<8;j++){ w1[j]=0.f; w2[j]=0.f; w3[j]=0.f; }
  for (int it=0; it<22; ++it){
    int t = t0 - 3 + it;
    #pragma unroll
    for (int j=0;j<8;j++){ w0[j]=w1[j]; w1[j]=w2[j]; w2[j]=w3[j]; }
    if (t >= 0 && t < LSEQ){
      uint4 xv = *(const uint4*)(zx + ((size_t)b*LSEQ + t)*NPAD + DINNER + c0);
      const unsigned short* xs = (const unsigned short*)&xv;
      #pragma unroll
      for (int j=0;j<8;j++) w3[j] = b2f(xs[j]);
      if (t >= t0 && t < t0+16){
        uint4 zv = *(const uint4*)(zx + ((size_t)b*LSEQ + t)*NPAD + c0);
        *(uint4*)(zcomp + ((size_t)b*LSEQ + t)*DINNER + c0) = zv;
      }
    } else {
      #pragma unroll
      for (int j=0;j<8;j++) w3[j] = 0.f;
    }
    if (t >= t0 && t < t0+16){
      float dtf = sdtf[t - t0blk][head];
      float v[8];
      #pragma unroll
      for (int j=0;j<8;j++){
        float a = bias8[j] + wk[0][j]*w0[j] + wk[1][j]*w1[j] + wk[2][j]*w2[j] + wk[3][j]*w3[j];
        v[j] = (a / (1.f + __expf(-a))) * dtf;
      }
      *(uint4*)(dtxb + ((size_t)b*LSEQ + t)*DINNER + c0) = pack8(v);
    }
    int tau = t - 3;
    if (tau >= t0 && tau < t0+16){
      float dtv = sdtb[tau - t0blk][head];
      float v[8];
      #pragma unroll
      for (int j=0;j<8;j++){
        float a = bias8[j] + wk[0][j]*w3[j] + wk[1][j]*w2[j] + wk[2][j]*w1[j] + wk[3][j]*w0[j];
        v[j] = (a / (1.f + __expf(-a))) * dtv;
      }
      *(uint4*)(dtxb + ((size_t)(BSZ+b)*LSEQ + (LSEQ-1-tau))*DINNER + c0) = pack8(v);
    }
  }
}

// ---------------- conv+silu for B/C channels, both directions ----------------
__global__ __launch_bounds__(256) void conv_bc_k(const unsigned short* __restrict__ zx,
    const float* __restrict__ conv_w, const float* __restrict__ conv_b,
    unsigned short* __restrict__ Bb, unsigned short* __restrict__ Cb){
  int b = blockIdx.y;
  int t0blk = blockIdx.x * 64;
  int tid = threadIdx.x;
  int slot = tid >> 4, cg = tid & 15;
  int c0 = cg*8;
  int ccol = DINNER + 1024 + c0;
  int cw = 1024 + c0;
  float wk[4][8], bias8[8];
  #pragma unroll
  for (int k=0;k<4;k++)
    #pragma unroll
    for (int j=0;j<8;j++) wk[k][j] = conv_w[k*CONVDIM + cw + j];
  #pragma unroll
  for (int j=0;j<8;j++) bias8[j] = conv_b[cw + j];
  int t0 = t0blk + slot*4;
  float w0[8],w1[8],w2[8],w3[8];
  #pragma unroll
  for (int j=0;j<8;j++){ w1[j]=0.f; w2[j]=0.f; w3[j]=0.f; }
  for (int it=0; it<10; ++it){
    int t = t0 - 3 + it;
    #pragma unroll
    for (int j=0;j<8;j++){ w0[j]=w1[j]; w1[j]=w2[j]; w2[j]=w3[j]; }
    if (t >= 0 && t < LSEQ){
      uint4 xv = *(const uint4*)(zx + ((size_t)b*LSEQ + t)*NPAD + ccol);
      const unsigned short* xs = (const unsigned short*)&xv;
      #pragma unroll
      for (int j=0;j<8;j++) w3[j] = b2f(xs[j]);
    } else {
      #pragma unroll
      for (int j=0;j<8;j++) w3[j] = 0.f;
    }
    if (t >= t0 && t < t0+4){
      float v[8];
      #pragma unroll
      for (int j=0;j<8;j++){
        float a = bias8[j] + wk[0][j]*w0[j] + wk[1][j]*w1[j] + wk[2][j]*w2[j] + wk[3][j]*w3[j];
        v[j] = a / (1.f + __expf(-a));
      }
      size_t tok = (size_t)b*LSEQ + t;
      if (c0 < 64) *(uint4*)(Bb + tok*DSTATE + c0)      = pack8(v);
      else         *(uint4*)(Cb + tok*DSTATE + (c0-64)) = pack8(v);
    }
    int tau = t - 3;
    if (tau >= t0 && tau < t0+4){
      float v[8];
      #pragma unroll
      for (int j=0;j<8;j++){
        float a = bias8[j] + wk[0][j]*w3[j] + wk[1][j]*w2[j] + wk[2][j]*w1[j] + wk[3][j]*w0[j];
        v[j] = a / (1.f + __expf(-a));
      }
      size_t tok = (size_t)(BSZ+b)*LSEQ + (LSEQ-1-tau);
      if (c0 < 64) *(uint4*)(Bb + tok*DSTATE + c0)      = pack8(v);
      else         *(uint4*)(Cb + tok*DSTATE + (c0-64)) = pack8(v);
    }
  }
}

// ---- per-wave slice of a 64x64x64 bf16 GEMM: acc[mt] += A(rows mt*16+l15) * B(row-tile nt)^T.
// nt is this wave's N-tile. Swizzled layout (S*): (r,c) at r*72 + ((c>>3)^((r>>3)&7))*8 + (c&7).
template<int SA, int SB>
__device__ inline void gemm64w(const unsigned short* Ab, const unsigned short* Bb_,
                               int l15, int q, int nt, f32x4 acc[4]){
  #pragma unroll
  for (int ks=0; ks<2; ks++){
    short8 af[4], bf;
    #pragma unroll
    for (int mt=0;mt<4;mt++){
      int r = mt*16 + l15;
      int c = ks*4 + q; if (SA) c ^= (r>>3)&7;
      af[mt] = *(const short8*)(Ab + r*72 + c*8);
    }
    {
      int r = nt*16 + l15;
      int c = ks*4 + q; if (SB) c ^= (r>>3)&7;
      bf = *(const short8*)(Bb_ + r*72 + c*8);
    }
    #pragma unroll
    for (int mt=0;mt<4;mt++)
      acc[mt] = __builtin_amdgcn_mfma_f32_16x16x32_bf16(af[mt], bf, acc[mt], 0,0,0);
  }
}

// ---------------- SSD pass 1, 4-wave cooperative (256 thr): Y_intra + local state G ----
// Each wave owns N-tile nt=w of every 64x64 gemm (8 MFMAs each) and i in {2w,2w+1}
// of every load/store loop. Residency: 28 KiB LDS -> 5 blocks x 4 waves = 20 waves/CU
// (vs 5 at 1-wave blocks). Barrier ledger in comments.
__global__ __launch_bounds__(256) void ssd1_k(const float* __restrict__ dAb,
    const unsigned short* __restrict__ dtxb, const unsigned short* __restrict__ Bb,
    const unsigned short* __restrict__ Cb,
    unsigned short* __restrict__ y0, unsigned short* __restrict__ y1,
    unsigned short* __restrict__ hbuf, float* __restrict__ Pch, float* __restrict__ ebuf){
  int ch = blockIdx.x, h = blockIdx.y, z = blockIdx.z;
  int d = z >> 1, b = z & 1;
  int tid = threadIdx.x;
  int lane = tid & 63, w = tid >> 6;
  int l15 = lane & 15, q = lane >> 4;
  int tr = lane >> 3, cb8 = (lane & 7)*8;
  int m7 = lane & 7;
  size_t tokb = (size_t)z*LSEQ + (size_t)ch*64;
  size_t zhc = ((size_t)z*NHEADS + h)*NCH + ch;
  __shared__ __align__(16) unsigned short S1[64*72];
  __shared__ __align__(16) unsigned short S2[64*72];
  __shared__ __align__(16) unsigned short S3[64*72];
  __shared__ float Lb[64];
  // scan replicated per wave (identical inputs); wave 0 publishes
  float L = fmaxf(logf(dAb[(tokb + lane)*NHEADS + h]), -60.f);
  #pragma unroll
  for (int off=1; off<64; off<<=1){
    float v = __shfl_up(L, off);
    if (lane >= off) L += v;
  }
  if (w == 0){
    Lb[lane] = L;
    float e = __expf(L);
    ebuf[zhc*64 + lane] = e;
    if (lane == 63) Pch[zhc] = e;
  }
  // loads: wave w covers i in {2w, 2w+1}
  #pragma unroll
  for (int ii=0; ii<2; ii++){
    int i = w*2 + ii; int t = i*8 + tr;
    *(uint4*)&S1[t*72 + cb8] = *(const uint4*)(Cb + (tokb+t)*DSTATE + cb8);
    *(uint4*)&S2[t*72 + cb8] = *(const uint4*)(Bb + (tokb+t)*DSTATE + cb8);
    uint4 xv = *(const uint4*)(dtxb + (tokb+t)*DINNER + (size_t)h*64 + cb8);
    const unsigned short* xs = (const unsigned short*)&xv;
    int csw = ((i ^ m7) << 3) + tr;
    #pragma unroll
    for (int j=0;j<8;j++) S3[(cb8+j)*72 + csw] = xs[j];
  }
  __syncthreads();                       // B0: loads + Lb visible
  // gemm1: sa[mt] for nt=w   (C . B^T slice)
  f32x4 sa[4];
  #pragma unroll
  for (int i=0;i<4;i++) sa[i] = (f32x4){0.f,0.f,0.f,0.f};
  gemm64w<0,0>(S1, S2, l15, q, w, sa);
  float Lsv = Lb[w*16 + l15];
  __syncthreads();                       // B1: all waves' S1/S2 reads retired -> P may overwrite S1
  int sch = l15 >> 3, sin = l15 & 7;
  #pragma unroll
  for (int mt=0;mt<4;mt++){
    #pragma unroll
    for (int r=0;r<4;r++){
      int t = mt*16 + q*4 + r;
      int trow = (t>>3)&7;
      float Lt = Lb[t];
      int s = w*16 + l15;
      float v = (t >= s) ? __expf(Lt - Lsv) * sa[mt][r] : 0.f;
      S1[t*72 + (((w*2 + sch) ^ trow)<<3) + sin] = f2b(v);   // swizzled P
    }
  }
  __syncthreads();                       // B2: P complete
  // gemm2: ya[mt] for pt=w   (P . dtx^T slice)
  f32x4 ya[4];
  #pragma unroll
  for (int i=0;i<4;i++) ya[i] = (f32x4){0.f,0.f,0.f,0.f};
  gemm64w<1,1>(S1, S3, l15, q, w, ya);
  #pragma unroll
  for (int mt=0;mt<4;mt++)
    #pragma unroll
    for (int r=0;r<4;r++)
      S2[(mt*16+q*4+r)*72 + w*16 + l15] = f2b(ya[mt][r]);
  __syncthreads();                       // B3: ya staged in S2 (and all S1 reads of gemm2 retired)
  unsigned short* yb = d ? y1 : y0;
  #pragma unroll
  for (int ii=0; ii<2; ii++){
    int i = w*2 + ii; int t = i*8 + tr; int g = ch*64 + t;
    int tph = d ? (LSEQ-1-g) : g;
    *(uint4*)(yb + ((size_t)b*LSEQ + tph)*DINNER + (size_t)h*64 + cb8) = *(uint4*)&S2[t*72 + cb8];
  }
  __syncthreads();                       // B4: y-out reads done -> decay-B may overwrite S2
  float L63 = Lb[63];
  #pragma unroll
  for (int ii=0; ii<2; ii++){
    int i = w*2 + ii; int s = i*8 + tr;
    float wgt = __expf(L63 - Lb[s]);
    uint4 bv = *(const uint4*)(Bb + (tokb+s)*DSTATE + cb8);
    const unsigned short* bs = (const unsigned short*)&bv;
    int csw = ((i ^ m7) << 3) + tr;
    #pragma unroll
    for (int j=0;j<8;j++) S2[(cb8+j)*72 + csw] = f2b(wgt * b2f(bs[j]));
  }
  __syncthreads();                       // B5: decay-B staged
  // gemm3: ga[pt] for nt=w   (dtx^T . decayB slice)
  f32x4 ga[4];
  #pragma unroll
  for (int i=0;i<4;i++) ga[i] = (f32x4){0.f,0.f,0.f,0.f};
  gemm64w<1,1>(S3, S2, l15, q, w, ga);
  #pragma unroll
  for (int pt=0;pt<4;pt++)
    #pragma unroll
    for (int r=0;r<4;r++)
      S1[(pt*16+q*4+r)*72 + w*16 + l15] = f2b(ga[pt][r]);
  __syncthreads();                       // B6: G staged in S1
  #pragma unroll
  for (int ii=0; ii<2; ii++){
    int i = w*2 + ii; int p = i*8 + tr;
    *(uint4*)(hbuf + zhc*4096 + (size_t)p*64 + cb8) = *(uint4*)&S1[p*72 + cb8];
  }
}

// ---------------- combine chunk states, IN PLACE (4-way over state dim, prefetched) ----
__global__ __launch_bounds__(256) void comb_k(unsigned short* __restrict__ hbuf,
    const float* __restrict__ Pch){
  int u = blockIdx.x; int tid = threadIdx.x;
  int kb = blockIdx.y * 4;
  size_t base0 = ((size_t)u*NCH)*4096;
  float hreg[4];
  unsigned short ccur[4], cnxt[4] = {0,0,0,0};
  #pragma unroll
  for (int k=0;k<4;k++){ hreg[k]=0.f; ccur[k] = hbuf[base0 + tid + (size_t)(kb+k)*256]; }
  float Pc = Pch[(size_t)u*NCH], Pn = 0.f;
  for (int ch=0; ch<NCH; ch++){
    size_t base = base0 + (size_t)ch*4096;
    if (ch+1 < NCH){
      size_t bnx = base + 4096;
      #pragma unroll
      for (int k=0;k<4;k++) cnxt[k] = hbuf[bnx + tid + (size_t)(kb+k)*256];
      Pn = Pch[(size_t)u*NCH + ch + 1];
    }
    #pragma unroll
    for (int k=0;k<4;k++){
      hbuf[base + tid + (size_t)(kb+k)*256] = f2b(hreg[k]);
      hreg[k] = hreg[k]*Pc + b2f(ccur[k]);
    }
    #pragma unroll
    for (int k=0;k<4;k++) ccur[k] = cnxt[k];
    Pc = Pn;
  }
}

// ---------------- SSD pass 2, 4-wave cooperative: Y += diag(e) C h_in^T + D*xh ------
__global__ __launch_bounds__(256) void ssd2_k(const unsigned short* __restrict__ Cb,
    const unsigned short* __restrict__ hbuf, const unsigned short* __restrict__ dtxb,
    const float* __restrict__ dtb, const float* __restrict__ ebuf, const float* __restrict__ Dh,
    unsigned short* __restrict__ y0, unsigned short* __restrict__ y1){
  int ch = blockIdx.x, h = blockIdx.y, z = blockIdx.z;
  int d = z >> 1, b = z & 1;
  int tid = threadIdx.x;
  int lane = tid & 63, w = tid >> 6;
  int l15 = lane & 15, q = lane >> 4;
  int tr = lane >> 3, cb8 = (lane & 7)*8;
  size_t tokb = (size_t)z*LSEQ + (size_t)ch*64;
  size_t zhc = ((size_t)z*NHEADS + h)*NCH + ch;
  __shared__ __align__(16) unsigned short S1[64*72];
  __shared__ __align__(16) unsigned short S2[64*72];
  __shared__ __align__(16) unsigned short S3[64*72];
  __shared__ float eb2[64], dti[64];
  if (w == 0){
    eb2[lane] = ebuf[zhc*64 + lane];
    dti[lane] = 1.f / dtb[(tokb + lane)*NHEADS + h];
  }
  float Dv = Dh[h];
  #pragma unroll
  for (int ii=0; ii<2; ii++){
    int i = w*2 + ii; int t = i*8 + tr;
    *(uint4*)&S1[t*72 + cb8] = *(const uint4*)(Cb + (tokb+t)*DSTATE + cb8);
    *(uint4*)&S2[t*72 + cb8] = *(const uint4*)(hbuf + zhc*4096 + (size_t)t*64 + cb8);
  }
  __syncthreads();                       // loads + eb2/dti visible
  f32x4 acc[4];
  #pragma unroll
  for (int i=0;i<4;i++) acc[i] = (f32x4){0.f,0.f,0.f,0.f};
  gemm64w<0,0>(S1, S2, l15, q, w, acc);  // acc[mt] for pt=w
  unsigned short* yb = d ? y1 : y0;
  #pragma unroll
  for (int mt=0;mt<4;mt++){
    #pragma unroll
    for (int r=0;r<4;r++){
      int t = mt*16 + q*4 + r; int g = ch*64 + t;
      int tph = d ? (LSEQ-1-g) : g;
      size_t rowb = ((size_t)b*LSEQ + tph)*DINNER + (size_t)h*64;
      size_t dxb_ = (tokb + t)*DINNER + (size_t)h*64;
      float et = eb2[t], di = dti[t];
      int p = w*16 + l15;
      float v = acc[mt][r]*et + b2f(yb[rowb + p]) + Dv * b2f(dtxb[dxb_ + p]) * di;
      S3[t*72 + p] = f2b(v);
    }
  }
  __syncthreads();                       // S3 complete across waves
  #pragma unroll
  for (int ii=0; ii<2; ii++){
    int i = w*2 + ii; int t = i*8 + tr; int g = ch*64 + t;
    int tph = d ? (LSEQ-1-g) : g;
    *(uint4*)(yb + ((size_t)b*LSEQ + tph)*DINNER + (size_t)h*64 + cb8) = *(uint4*)&S3[t*72 + cb8];
  }
}

// ---------------- gate: g=y*silu(z), per-dir rmsnorm, sum, ->bf16 ----------------
__global__ __launch_bounds__(256) void gate_k(const unsigned short* __restrict__ y0,
    const unsigned short* __restrict__ y1, const unsigned short* __restrict__ zcomp,
    const float* __restrict__ mnw, unsigned short* __restrict__ gsum){
  int tok = blockIdx.x; int tid = threadIdx.x;
  __shared__ float g0s[DINNER], g1s[DINNER];
  float ss0 = 0.f, ss1 = 0.f;
  for (int i=0;i<4;i++){
    int c = tid + i*256;
    float z = b2f(zcomp[(size_t)tok*DINNER + c]);
    float sz = z / (1.f + __expf(-z));
    float g0 = b2f(y0[(size_t)tok*DINNER + c]) * sz;
    float g1 = b2f(y1[(size_t)tok*DINNER + c]) * sz;
    g0s[c] = g0; g1s[c] = g1;
    ss0 += g0*g0; ss1 += g1*g1;
  }
  for (int m=32;m>=1;m>>=1){ ss0 += __shfl_xor(ss0,m); ss1 += __shfl_xor(ss1,m); }
  __shared__ float w0[4], w1[4];
  int wave = tid>>6, lane = tid&63;
  if (lane==0){ w0[wave]=ss0; w1[wave]=ss1; }
  __syncthreads();
  ss0 = w0[0]+w0[1]+w0[2]+w0[3];
  ss1 = w1[0]+w1[1]+w1[2]+w1[3];
  float r0 = rsqrtf(ss0*(1.f/DINNER) + 1e-5f);
  float r1 = rsqrtf(ss1*(1.f/DINNER) + 1e-5f);
  for (int i=0;i<4;i++){
    int c = tid + i*256;
    gsum[(size_t)tok*DINNER + c] = f2b((g0s[c]*r0 + g1s[c]*r1) * mnw[c]);
  }
}

extern "C" void kernel_launch(void* const* d_in, const int* in_sizes, int n_in,
                              void* d_out, int out_size, void* d_ws, size_t ws_size,
                              hipStream_t stream){
  const float* x       = (const float*)d_in[0];
  const float* nin_w   = (const float*)d_in[1];
  const float* nin_b   = (const float*)d_in[2];
  const float* nout_w  = (const float*)d_in[3];
  const float* nout_b  = (const float*)d_in[4];
  const float* in_w    = (const float*)d_in[5];
  const float* conv_w  = (const float*)d_in[6];
  const float* conv_b  = (const float*)d_in[7];
  const float* dt_bias = (const float*)d_in[8];
  const float* A_log   = (const float*)d_in[9];
  const float* D_h     = (const float*)d_in[10];
  const float* mnorm_w = (const float*)d_in[11];
  const float* out_w   = (const float*)d_in[12];
  const float* ff_w1   = (const float*)d_in[13];
  const float* ff_b1   = (const float*)d_in[14];
  const float* ff_w2   = (const float*)d_in[15];
  const float* ff_b2   = (const float*)d_in[16];
  float* out = (float*)d_out;

  char* ws = (char*)d_ws;
  size_t off = 0;
  auto alloc = [&](size_t bytes)->char*{
    char* p = ws + off; off = (off + bytes + 255) & ~(size_t)255; return p; };
  unsigned short* xn_bf = (unsigned short*)alloc((size_t)NTOK*DMODEL*2);    // 8.4 MB
  unsigned short* in_wT = (unsigned short*)alloc((size_t)NPAD*DMODEL*2);
  unsigned short* out_wT= (unsigned short*)alloc((size_t)DMODEL*DINNER*2);
  unsigned short* w1T   = (unsigned short*)alloc((size_t)2048*DMODEL*2);
  unsigned short* w2T   = (unsigned short*)alloc((size_t)DMODEL*2048*2);
  unsigned short* zx    = (unsigned short*)alloc((size_t)NTOK*NPAD*2);      // 37.7 MB
  unsigned short* zcomp = (unsigned short*)alloc((size_t)NTOK*DINNER*2);    // 16.8 MB
  float*          dAb   = (float*)alloc((size_t)2*NTOK*NHEADS*4);
  float*          dtb   = (float*)alloc((size_t)2*NTOK*NHEADS*4);
  unsigned short* Bb    = (unsigned short*)alloc((size_t)2*NTOK*DSTATE*2);
  unsigned short* Cb    = (unsigned short*)alloc((size_t)2*NTOK*DSTATE*2);
  unsigned short* dtxb  = (unsigned short*)alloc((size_t)2*NTOK*DINNER*2);  // 33.6 MB
  unsigned short* y0    = (unsigned short*)alloc((size_t)NTOK*DINNER*2);    // 16.8 MB
  unsigned short* y1    = (unsigned short*)alloc((size_t)NTOK*DINNER*2);    // 16.8 MB (contiguous after y0)
  float*          Pch   = (float*)alloc((size_t)64*NCH*4);
  float*          ebuf  = (float*)alloc((size_t)64*NCH*64*4);               // 1.05 MB
  size_t need = off;
  if (need > ws_size) return;  // fail absmax cleanly instead of faulting

  // aliases into sequentially-dead regions (stream order makes each safe):
  unsigned short* hbuf  = zx;        // chunk states; zx dead after conv kernels
  unsigned short* gsum  = dtxb;      // dtxb dead after ssd2_k
  float* mp01 = (float*)zx;          // out_proj partials z=0,1 (hbuf dead after ssd2)
  float* mp23 = (float*)y0;          // out_proj partials z=2,3 (y0+y1 dead after gate)
  unsigned short* m_bf  = xn_bf;     // LN4 out (xn_bf dead after in_proj)
  unsigned short* h1    = zx;        // ff1 out (mp01 dead after LN4)
  float* fp01 = (float*)dtxb;        // ff2 partials z=0,1 (gsum dead after out_proj)
  float* fp23 = (float*)y0;          // ff2 partials z=2,3 (mp23 dead after LN4)

  // weight transposes -> bf16 [N][K]
  wconv_t<<<dim3(NPAD/32,   DMODEL/32), 256, 0, stream>>>(in_w,  in_wT,  DMODEL, DPROJ,  NPAD);
  wconv_t<<<dim3(DMODEL/32, DINNER/32), 256, 0, stream>>>(out_w, out_wT, DINNER, DMODEL, DMODEL);
  wconv_t<<<dim3(2048/32,   DMODEL/32), 256, 0, stream>>>(ff_w1, w1T,    DMODEL, 2048,   2048);
  wconv_t<<<dim3(DMODEL/32, 2048/32),   256, 0, stream>>>(ff_w2, w2T,    2048,   DMODEL, DMODEL);
  // LN in -> bf16
  layernorm_k<<<NTOK, 256, 0, stream>>>(x, nin_w, nin_b, xn_bf);
  // in_proj -> bf16 zx   [128x256, 2 blocks/CU]
  gemm128_k<<<dim3(NPAD/256, NTOK/128, 1), 512, 0, stream>>>(xn_bf, in_wT, zx, nullptr, NTOK, NPAD, DMODEL, DMODEL, 3, nullptr);
  // dt/dA then conv (both directions from one pass) + z compaction
  dt_k<<<dim3(LSEQ/16, BSZ), 256, 0, stream>>>(zx, dt_bias, A_log, dAb, dtb);
  conv_x_k<<<dim3(LSEQ/32, BSZ), 256, 0, stream>>>(zx, conv_w, conv_b, dtb, dtxb, zcomp);
  conv_bc_k<<<dim3(LSEQ/64, BSZ), 256, 0, stream>>>(zx, conv_w, conv_b, Bb, Cb);
  // chunked SSD: intra-chunk (MFMA, 4-wave) -> combine -> inter-chunk (MFMA, 4-wave)
  ssd1_k<<<dim3(NCH, NHEADS, 2*BSZ), 256, 0, stream>>>(dAb, dtxb, Bb, Cb, y0, y1, hbuf, Pch, ebuf);
  comb_k<<<dim3(64, 4), 256, 0, stream>>>(hbuf, Pch);
  ssd2_k<<<dim3(NCH, NHEADS, 2*BSZ), 256, 0, stream>>>(Cb, hbuf, dtxb, dtb, ebuf, D_h, y0, y1);
  // gate + per-dir rmsnorm + sum (linearity: single out_proj GEMM)
  gate_k<<<NTOK, 256, 0, stream>>>(y0, y1, zcomp, mnorm_w, gsum);
  // out_proj: split-K=4 -> f32 partials mp01[2], mp23[2]
  gemm128_k<<<dim3(DMODEL/256, NTOK/128, 4), 512, 0, stream>>>(gsum, out_wT, mp01, mp23, NTOK, DMODEL, DINNER, 256, 0, nullptr);
  // LN out over sum of 4 partials -> bf16 (m_bf = xn_bf region)
  layernorm4_k<<<NTOK, 256, 0, stream>>>(mp01, mp01 + (size_t)NTOK*DMODEL, mp23, mp23 + (size_t)NTOK*DMODEL, nout_w, nout_b, m_bf);
  // ff1 + gelu -> bf16
  gemm128_k<<<dim3(2048/256, NTOK/128, 1), 512, 0, stream>>>(m_bf, w1T, h1, nullptr, NTOK, 2048, DMODEL, DMODEL, 1, ff_b1);
  // ff2: split-K=4 -> f32 partials fp01[2], fp23[2]
  gemm128_k<<<dim3(DMODEL/256, NTOK/128, 4), 512, 0, stream>>>(h1, w2T, fp01, fp23, NTOK, DMODEL, 2048, 512, 0, nullptr);
  // reduce partials + bias + residual -> f32 out
  reduce4_k<<<2048, 256, 0, stream>>>(fp01, fp23, ff_b2, x, out);
}